// Round 11
// baseline (2241.934 us; speedup 1.0000x reference)
//
#include <hip/hip_runtime.h>
#include <hip/hip_bf16.h>
#include <stdint.h>

#define DMODEL 2048
#define QDIM   2048
#define KVDIM  512
#define QKVDIM 3072
#define DFF    8192
#define NSTEPS 5

typedef __bf16 bf16_t;
typedef __attribute__((ext_vector_type(8))) __bf16 bf16x8;
typedef __attribute__((ext_vector_type(4))) float f32x4;

// global -> LDS direct DMA, 16B per lane. LDS dest is wave-uniform base;
// HW writes lane i at base + i*16. Requires linear (unpadded) LDS layout.
#define GLL16(g, l)                                                         \
  __builtin_amdgcn_global_load_lds(                                          \
      (const __attribute__((address_space(1))) void*)(g),                    \
      (__attribute__((address_space(3))) void*)(l), 16, 0, 0)

#define MFMA_BF16 __builtin_amdgcn_mfma_f32_16x16x32_bf16

__device__ __forceinline__ float wave_sum(float v) {
#pragma unroll
  for (int o = 32; o > 0; o >>= 1) v += __shfl_xor(v, o, 64);
  return v;
}

// ---------------- index building (handles int32 or int64 length arrays) ----
__global__ void build_idx_kernel(const int* __restrict__ seq, const int* __restrict__ inst,
                                 int B, int* __restrict__ idx, int* __restrict__ dN, int nmax) {
  __shared__ int sbase[64], soff[64], scnt[64], snb;
  if (threadIdx.x == 0) {
    bool is64 = (B >= 2);
    for (int i = 0; i < B && is64; ++i) {
      if (i & 1) { if (seq[i] != 0 || inst[i] != 0) is64 = false; }
      else       { if (seq[i] == 0) is64 = false; }
    }
    int off = 0, row = 0, nb = (B < 64 ? B : 64);
    for (int b = 0; b < nb; ++b) {
      int s = is64 ? seq[2 * b] : seq[b];
      int i = is64 ? inst[2 * b] : inst[b];
      sbase[b] = row; soff[b] = off + i - 1; scnt[b] = s - i;
      row += s - i; off += s;
    }
    snb = nb;
    *dN = row < nmax ? row : nmax;
  }
  __syncthreads();
  int nb = snb;
  for (int b = 0; b < nb; ++b) {
    int cnt = scnt[b], base = sbase[b], o0 = soff[b];
    for (int t = threadIdx.x; t < cnt; t += blockDim.x) {
      int r = base + t;
      if (r < nmax) idx[r] = o0 + t;
    }
  }
}

// ---------------- gather rows into h0 (fp32) -------------------------------
__global__ __launch_bounds__(256)
void gather_kernel(const float* __restrict__ hs, const int* __restrict__ idx,
                   float* __restrict__ h0, const int* __restrict__ dN) {
  int r = blockIdx.x; if (r >= *dN) return;
  const float4* in = (const float4*)(hs + (size_t)idx[r] * DMODEL);
  float4* out = (float4*)(h0 + (size_t)r * DMODEL);
  out[threadIdx.x]       = in[threadIdx.x];
  out[threadIdx.x + 256] = in[threadIdx.x + 256];
}

// ---------------- fp32 -> bf16 transpose of a weight matrix ----------------
// W is [K][Nc] row-major fp32, Wt is [Nc][K] row-major bf16
__global__ __launch_bounds__(256)
void wtrans_kernel(const float* __restrict__ W, bf16_t* __restrict__ Wt, int K, int Nc) {
  __shared__ float tile[32][33];
  int c0 = blockIdx.x * 32, k0 = blockIdx.y * 32;
  int tx = threadIdx.x & 31, ty = threadIdx.x >> 5;
#pragma unroll
  for (int yy = 0; yy < 4; ++yy)
    tile[ty + 8 * yy][tx] = W[(size_t)(k0 + ty + 8 * yy) * Nc + c0 + tx];
  __syncthreads();
#pragma unroll
  for (int yy = 0; yy < 4; ++yy)
    Wt[(size_t)(c0 + ty + 8 * yy) * K + k0 + tx] = (bf16_t)tile[tx][ty + 8 * yy];
}

// ---------------- RMSNorm: fp32 row -> bf16 row ----------------------------
__global__ __launch_bounds__(256)
void rmsnorm_kernel(const float* __restrict__ h, long hstride, const float* __restrict__ w,
                    bf16_t* __restrict__ x, const int* __restrict__ dN) {
  int r = blockIdx.x; if (r >= *dN) return;
  const float* row = h + (size_t)r * hstride;
  int t = threadIdx.x;
  float4 v0 = ((const float4*)row)[2 * t];
  float4 v1 = ((const float4*)row)[2 * t + 1];
  float ss = v0.x*v0.x + v0.y*v0.y + v0.z*v0.z + v0.w*v0.w
           + v1.x*v1.x + v1.y*v1.y + v1.z*v1.z + v1.w*v1.w;
  ss = wave_sum(ss);
  __shared__ float part[4];
  if ((t & 63) == 0) part[t >> 6] = ss;
  __syncthreads();
  float inv = rsqrtf((part[0] + part[1] + part[2] + part[3]) * (1.0f / DMODEL) + 1e-6f);
  const float4* wv = (const float4*)w;
  float4 w0 = wv[2 * t], w1 = wv[2 * t + 1];
  union { bf16_t b[8]; uint4 q; } u;
  u.b[0] = (bf16_t)(v0.x * inv * w0.x);
  u.b[1] = (bf16_t)(v0.y * inv * w0.y);
  u.b[2] = (bf16_t)(v0.z * inv * w0.z);
  u.b[3] = (bf16_t)(v0.w * inv * w0.w);
  u.b[4] = (bf16_t)(v1.x * inv * w1.x);
  u.b[5] = (bf16_t)(v1.y * inv * w1.y);
  u.b[6] = (bf16_t)(v1.z * inv * w1.z);
  u.b[7] = (bf16_t)(v1.w * inv * w1.w);
  *(uint4*)(x + (size_t)r * DMODEL + t * 8) = u.q;
}

// ---------------- RoPE(k at pos p) + append k,v to cache -------------------
__global__ __launch_bounds__(512)
void rope_cache_kernel(const bf16_t* __restrict__ qkv, bf16_t* __restrict__ kc,
                       bf16_t* __restrict__ vc, int p, const int* __restrict__ dN) {
  int r = blockIdx.x; if (r >= *dN) return;
  int d = threadIdx.x;           // 0..511
  int e = d & 63, fi = e & 31;
  size_t qb = (size_t)r * QKVDIM;
  float k  = (float)qkv[qb + QDIM + d];
  float kp = (float)qkv[qb + QDIM + (d ^ 32)];
  float ang = (float)p * expf((float)fi * -0.28782313662425576f); // -ln(1e4)/32
  float cv, sv; sincosf(ang, &sv, &cv);
  float kr = k * cv + ((e < 32) ? -kp : kp) * sv;
  size_t cb = ((size_t)r * NSTEPS + p) * KVDIM + d;
  kc[cb] = (bf16_t)kr;
  vc[cb] = qkv[qb + QDIM + KVDIM + d];
}

// ---------------- attention at position p (one wave per row,head) ----------
__global__ __launch_bounds__(256)
void attn_kernel(const bf16_t* __restrict__ qkv, const bf16_t* __restrict__ kc,
                 const bf16_t* __restrict__ vc, bf16_t* __restrict__ o,
                 int p, const int* __restrict__ dN) {
  int r = blockIdx.x; if (r >= *dN) return;
  int wid = threadIdx.x >> 6, lane = threadIdx.x & 63;
  int head = blockIdx.y * 4 + wid;
  int kh = head >> 2;
  float q = (float)qkv[(size_t)r * QKVDIM + head * 64 + lane];
  int fi = lane & 31;
  float ang = (float)p * expf((float)fi * -0.28782313662425576f);
  float cv, sv; sincosf(ang, &sv, &cv);
  float qp = __shfl_xor(q, 32, 64);
  float qr = q * cv + ((lane < 32) ? -qp : qp) * sv;
  size_t cbase = (size_t)r * NSTEPS * KVDIM + kh * 64 + lane;
  float s[NSTEPS];
#pragma unroll
  for (int j = 0; j < NSTEPS; ++j) {
    s[j] = -1e30f;
    if (j <= p) {
      float kj = (float)kc[cbase + (size_t)j * KVDIM];
      s[j] = wave_sum(qr * kj) * 0.125f;
    }
  }
  float m = s[0];
#pragma unroll
  for (int j = 1; j < NSTEPS; ++j) m = fmaxf(m, s[j]);
  float aw[NSTEPS]; float den = 0.f;
#pragma unroll
  for (int j = 0; j < NSTEPS; ++j) { aw[j] = (j <= p) ? expf(s[j] - m) : 0.f; den += aw[j]; }
  float oa = 0.f;
#pragma unroll
  for (int j = 0; j < NSTEPS; ++j)
    if (j <= p) oa += aw[j] * (float)vc[cbase + (size_t)j * KVDIM];
  o[(size_t)r * QDIM + head * 64 + lane] = (bf16_t)(oa / den);
}

// ---------------- 128x128 2-phase GEMM (QKV / Wo) --------------------------
// MODE 0: outb = bf16(acc);  MODE 1: outf = res + acc  (fp32).
template <int MODE>
__global__ __launch_bounds__(256)
void gemm_kernel(const bf16_t* __restrict__ A, const bf16_t* __restrict__ Bt, int K,
                 const int* __restrict__ dN,
                 float* __restrict__ outf, long ostride,
                 const float* __restrict__ res, long rstride,
                 bf16_t* __restrict__ outb, long obstride) {
  const int N = *dN;
  const int brow = blockIdx.y * 128, bcol = blockIdx.x * 128;
  if (brow >= N) return;

  __shared__ __align__(16) bf16_t As[2][128 * 32];
  __shared__ __align__(16) bf16_t Bs[2][128 * 32];
  const int t = threadIdx.x;
  const int lane = t & 63, wid = t >> 6;
  const int wr = wid >> 1, wc = wid & 1;
  const int hi = lane >> 4, lo = lane & 15;
  const int xk = (lo >> 1) & 3;

  const int srow = wid * 16 + (lane >> 2);
  const int kseg = ((lane & 3) ^ ((lane >> 3) & 3)) * 8;
  const bf16_t* gA0 = A  + (size_t)(brow + srow) * K + kseg;
  const bf16_t* gA1 = gA0 + (size_t)64 * K;
  const bf16_t* gB0 = Bt + (size_t)(bcol + srow) * K + kseg;
  const bf16_t* gB1 = gB0 + (size_t)64 * K;
  const int lofs = wid * 512;

  f32x4 acc[4][4] = {};
  const int nk = K >> 5;

  GLL16(gA0, &As[0][lofs]);
  GLL16(gA1, &As[0][2048 + lofs]);
  GLL16(gB0, &Bs[0][lofs]);
  GLL16(gB1, &Bs[0][2048 + lofs]);

  int cur = 0;
  for (int kt = 0; kt < nk; ++kt) {
    __syncthreads();
    if (kt + 1 < nk) {
      const int k1 = (kt + 1) << 5;
      GLL16(gA0 + k1, &As[cur ^ 1][lofs]);
      GLL16(gA1 + k1, &As[cur ^ 1][2048 + lofs]);
      GLL16(gB0 + k1, &Bs[cur ^ 1][lofs]);
      GLL16(gB1 + k1, &Bs[cur ^ 1][2048 + lofs]);
    }
    bf16x8 af[4], bfr[4];
#pragma unroll
    for (int m = 0; m < 4; ++m)
      af[m] = *(const bf16x8*)(&As[cur][(wr * 64 + m * 16 + lo) * 32 + (hi ^ xk) * 8]);
#pragma unroll
    for (int n = 0; n < 4; ++n)
      bfr[n] = *(const bf16x8*)(&Bs[cur][(wc * 64 + n * 16 + lo) * 32 + (hi ^ xk) * 8]);
#pragma unroll
    for (int m = 0; m < 4; ++m)
#pragma unroll
      for (int n = 0; n < 4; ++n)
        acc[m][n] = MFMA_BF16(af[m], bfr[n], acc[m][n], 0, 0, 0);
    cur ^= 1;
  }

  const int rbase = brow + wr * 64 + hi * 4;
  const int cbase = bcol + wc * 64 + lo;
#pragma unroll
  for (int m = 0; m < 4; ++m) {
#pragma unroll
    for (int n = 0; n < 4; ++n) {
      const int col = cbase + n * 16;
#pragma unroll
      for (int j = 0; j < 4; ++j) {
        const int row = rbase + m * 16 + j;
        if (row < N) {
          float v = acc[m][n][j];
          if (MODE == 0) {
            outb[(size_t)row * obstride + col] = (bf16_t)v;
          } else {
            outf[(size_t)row * ostride + col] = res[(size_t)row * rstride + col] + v;
          }
        }
      }
    }
  }
}

// ---------------- 256x128 2-phase GEMM, BK=32, 2 blocks/CU -----------------
// Round-11: occupancy lever. BM=256, BN=128, BK=32; 8 waves as 4M x 2N
// (per-wave 64x64, acc[4][4] = 64 regs; ~120 unified regs/wave total);
// LDS 48 KiB static; __launch_bounds__(512,4) caps regs at 128 ->
// 2 blocks/CU (16 waves, 4/SIMD) for grids of 512 blocks. Cross-block
// wave overlap (m97/m114 mechanism) fills the per-block pipeline stalls
// that rounds 8-10 could not remove in-block.
// Sync skeleton = round-7's validated 2-phase/4-barrier structure.
// GLL counts: STG_A = 2, STG_B = 1 per wave. vmcnt re-derived:
//   prologue A0(2),B0(1),A1(2) = 5 in flight -> vmcnt(2) retires A0,B0;
//   steady: ph0 +B(t+1)[1] -> 3; ph1 +A(t+2)[2] -> 5; vmcnt(2) retires
//   A(t+1)+B(t+1) (read next iter), leaves A(t+2). Tail: vmcnt(0) at nt-2.
// WAR safety as in round 7: STG_B targets the other buf (its readers
// passed the prior iter's end barrier); STG_A targets current buf's
// A-region after ph0's two barriers (af reads complete before ph0 MFMA).
// Swizzle: slot ^= (row>>1)&3 both sides (measured conflict-free, r7).
// MODE 0: outb = bf16(acc); MODE 2: outb = bf16(silu(gateb)*acc);
// MODE 3: bf16 partial at outb + blockIdx.z * zstride.
template <int MODE>
__global__ __launch_bounds__(512, 4)
void gemm256b_kernel(const bf16_t* __restrict__ A, const bf16_t* __restrict__ Bt,
                     int krow, int kchunk, const int* __restrict__ dN,
                     long zstride,
                     bf16_t* __restrict__ outb, long obstride,
                     const bf16_t* __restrict__ gateb, long gstride) {
  const int N = *dN;
  const int brow = blockIdx.y * 256, bcol = blockIdx.x * 128;
  if (brow >= N) return;
  const size_t koff = (size_t)blockIdx.z * kchunk;

  __shared__ __align__(16) bf16_t As[2][256 * 32];   // 32 KiB
  __shared__ __align__(16) bf16_t Bs[2][128 * 32];   // 16 KiB

  const int t = threadIdx.x;
  const int lane = t & 63, wid = t >> 6;        // 8 waves
  const int wm = wid >> 1, wn = wid & 1;        // 4M x 2N
  const int hi = lane >> 4, lo = lane & 15;

  // staging: lane l -> row (l>>2) of its 16-row chunk, slot l&3; source k
  // pre-swizzled by ^((l>>3)&3) so LDS[r][s] = G[r][s ^ ((r>>1)&3)].
  const int swsrc = ((lane & 3) ^ ((lane >> 3) & 3)) << 3;
  const size_t aoffl = (size_t)(brow + (lane >> 2)) * krow + koff + swsrc;
  const size_t boffl = (size_t)(bcol + (lane >> 2)) * krow + koff + swsrc;
  const size_t arow0 = (size_t)(wid * 32) * krow;       // A rows wid*32+
  const size_t arow1 = (size_t)(wid * 32 + 16) * krow;  // A rows wid*32+16
  const size_t brw0  = (size_t)(wid * 16) * krow;       // B rows wid*16+
  const int lA0 = wid * 1024, lA1 = wid * 1024 + 512;
  const int lB0 = wid * 512;

  // read: slot' = hi ^ ((row>>1)&3); frag bases are multiples of 16
  const int rsl = (hi ^ ((lo >> 1) & 3)) * 8;
  const int abase = (wm * 64 + lo) * 32 + rsl;   // + m*512
  const int bbase = (wn * 64 + lo) * 32 + rsl;   // + n*512

  f32x4 acc[4][4] = {};
  const int nt = kchunk >> 5;                    // K-tiles of 32

#define STG_A(T, bb) do {                                        \
    const bf16_t* g_ = A + aoffl + ((size_t)(T) << 5);           \
    GLL16(g_ + arow0, &As[bb][lA0]);                             \
    GLL16(g_ + arow1, &As[bb][lA1]);                             \
  } while (0)
#define STG_B(T, bb) do {                                        \
    const bf16_t* g_ = Bt + boffl + ((size_t)(T) << 5);          \
    GLL16(g_ + brw0, &Bs[bb][lB0]);                              \
  } while (0)

  // prologue: A(0),B(0) -> buf0; A(1) -> buf1; retire A0,B0.
  STG_A(0, 0);
  STG_B(0, 0);
  STG_A(1, 1);
  asm volatile("s_waitcnt vmcnt(2)" ::: "memory");
  __builtin_amdgcn_s_barrier();
  __builtin_amdgcn_sched_barrier(0);

  for (int kt = 0; kt < nt; ++kt) {
    const int b = kt & 1;
    bf16x8 af[4], b0, b1;
    // ---------------- phase 0: n=0,1; stage B(t+1) -> other buf ----------
#pragma unroll
    for (int m = 0; m < 4; ++m)
      af[m] = *(const bf16x8*)(&As[b][abase + m * 512]);
    b0 = *(const bf16x8*)(&Bs[b][bbase]);
    b1 = *(const bf16x8*)(&Bs[b][bbase + 512]);
    if (kt + 1 < nt) STG_B(kt + 1, b ^ 1);
    __builtin_amdgcn_s_barrier();
    __builtin_amdgcn_sched_barrier(0);
    __builtin_amdgcn_s_setprio(1);
#pragma unroll
    for (int m = 0; m < 4; ++m) {
      acc[m][0] = MFMA_BF16(af[m], b0, acc[m][0], 0, 0, 0);
      acc[m][1] = MFMA_BF16(af[m], b1, acc[m][1], 0, 0, 0);
    }
    __builtin_amdgcn_s_setprio(0);
    __builtin_amdgcn_sched_barrier(0);
    __builtin_amdgcn_s_barrier();
    __builtin_amdgcn_sched_barrier(0);
    // ---------------- phase 1: n=2,3; stage A(t+2) -> current buf --------
    bf16x8 b2, b3;
    b2 = *(const bf16x8*)(&Bs[b][bbase + 1024]);
    b3 = *(const bf16x8*)(&Bs[b][bbase + 1536]);
    if (kt + 2 < nt) STG_A(kt + 2, b);
    __builtin_amdgcn_s_barrier();
    __builtin_amdgcn_sched_barrier(0);
    __builtin_amdgcn_s_setprio(1);
#pragma unroll
    for (int m = 0; m < 4; ++m) {
      acc[m][2] = MFMA_BF16(af[m], b2, acc[m][2], 0, 0, 0);
      acc[m][3] = MFMA_BF16(af[m], b3, acc[m][3], 0, 0, 0);
    }
    __builtin_amdgcn_s_setprio(0);
    __builtin_amdgcn_sched_barrier(0);
    if (kt == nt - 2) asm volatile("s_waitcnt vmcnt(0)" ::: "memory");
    else              asm volatile("s_waitcnt vmcnt(2)" ::: "memory");
    __builtin_amdgcn_s_barrier();
    __builtin_amdgcn_sched_barrier(0);
  }
#undef STG_A
#undef STG_B

  const int rbase = brow + wm * 64 + hi * 4;
  const int cbase = bcol + wn * 64 + lo;
  bf16_t* pb = (MODE == 3) ? outb + (size_t)blockIdx.z * zstride : outb;
#pragma unroll
  for (int m = 0; m < 4; ++m) {
#pragma unroll
    for (int n = 0; n < 4; ++n) {
      const int col = cbase + n * 16;
#pragma unroll
      for (int j = 0; j < 4; ++j) {
        const int row = rbase + m * 16 + j;
        if (row < N) {
          float v = acc[m][n][j];
          if (MODE == 2) {
            float g = (float)gateb[(size_t)row * gstride + col];
            float sg = g / (1.0f + expf(-g));
            pb[(size_t)row * obstride + col] = (bf16_t)(sg * v);
          } else {
            pb[(size_t)row * obstride + col] = (bf16_t)v;
          }
        }
      }
    }
  }
}

// ---------------- split-K reduce for down-proj -----------------------------
// fp32 out(stride NSTEPS*DMODEL) = res + sum_{z<4} bf16 part[z]  (ncols=DMODEL)
__global__ __launch_bounds__(256)
void reduce_down_kernel(const bf16_t* __restrict__ part, long zstride,
                        const float* __restrict__ res, float* __restrict__ out,
                        const int* __restrict__ dN) {
  int r = blockIdx.x; if (r >= *dN) return;
  const int c = threadIdx.x * 8;                // 256*8 == DMODEL exactly
  float s[8] = {};
#pragma unroll
  for (int z = 0; z < 4; ++z) {
    const bf16x8 v = *(const bf16x8*)(part + (size_t)z * zstride + (size_t)r * DMODEL + c);
#pragma unroll
    for (int j = 0; j < 8; ++j) s[j] += (float)v[j];
  }
  const float* rv = res + (size_t)r * DMODEL + c;
  float* o = out + (size_t)r * (NSTEPS * DMODEL) + c;
#pragma unroll
  for (int j = 0; j < 8; ++j) o[j] = s[j] + rv[j];
}

// ---------------------------------------------------------------------------
extern "C" void kernel_launch(void* const* d_in, const int* in_sizes, int n_in,
                              void* d_out, int out_size, void* d_ws, size_t ws_size,
                              hipStream_t stream) {
  const float* hs  = (const float*)d_in[0];
  const int*   seq = (const int*)d_in[1];
  const int*   ins = (const int*)d_in[2];
  const float* w_q = (const float*)d_in[3];
  const float* w_k = (const float*)d_in[4];
  const float* w_v = (const float*)d_in[5];
  const float* w_o = (const float*)d_in[6];
  const float* ln1 = (const float*)d_in[7];
  const float* ln2 = (const float*)d_in[8];
  const float* w_g = (const float*)d_in[9];
  const float* w_u = (const float*)d_in[10];
  const float* w_d = (const float*)d_in[11];
  const int  B     = in_sizes[1];
  const long total = (long)in_sizes[0] / DMODEL;

  const size_t WQKV_E = (size_t)QKVDIM * DMODEL;
  const size_t WO_E   = (size_t)DMODEL * DMODEL;
  const size_t WG_E   = (size_t)DFF * DMODEL;

  struct WS {
    int* dN; int* idx;
    bf16_t *Wqkv, *Wo, *Wg, *Wu, *Wd;
    bf16_t* kc; bf16_t* vc; float* hattn; bf16_t* gate;
    float* h0; bf16_t* x; bf16_t* qkv; bf16_t* o;     // transient tail region
    bf16_t* part;                                      // overlays the tail
    size_t bytes;
  };
  char* base = (char*)d_ws;
  auto mk = [&](long nm) {
    WS w; size_t o = 0;
    auto alloc = [&](size_t b) { char* p = base + o; o = (o + b + 255) & ~(size_t)255; return p; };
    // persistent-within-step buffers first
    w.dN    = (int*)alloc(4);
    w.idx   = (int*)alloc((size_t)nm * 4);
    w.Wqkv  = (bf16_t*)alloc(WQKV_E * 2);
    w.Wo    = (bf16_t*)alloc(WO_E * 2);
    w.Wg    = (bf16_t*)alloc(WG_E * 2);
    w.Wu    = (bf16_t*)alloc(WG_E * 2);
    w.Wd    = (bf16_t*)alloc(WG_E * 2);
    w.kc    = (bf16_t*)alloc((size_t)nm * NSTEPS * KVDIM * 2);
    w.vc    = (bf16_t*)alloc((size_t)nm * NSTEPS * KVDIM * 2);
    w.hattn = (float*)alloc((size_t)nm * DMODEL * 4);
    w.gate  = (bf16_t*)alloc((size_t)nm * DFF * 2);
    // transient tail: {h0, x, qkv, o} = nm * 22528 B, dead during down-GEMM.
    w.h0    = (float*)alloc((size_t)nm * DMODEL * 4);
    w.x     = (bf16_t*)alloc((size_t)nm * DMODEL * 2);
    w.qkv   = (bf16_t*)alloc((size_t)nm * QKVDIM * 2);
    w.o     = (bf16_t*)alloc((size_t)nm * DMODEL * 2);
    // down split-K partials: 4 * nm * DMODEL bf16 = nm*16384 B <= nm*22528 B
    w.part  = (bf16_t*)w.h0;
    w.bytes = o;
    return w;
  };
  long nm = ((total + 255) / 256) * 256;
  WS w = mk(nm);
  while (w.bytes > ws_size && nm > 256) { nm -= 256; w = mk(nm); }

  build_idx_kernel<<<1, 512, 0, stream>>>(seq, ins, B, w.idx, w.dN, (int)nm);
  gather_kernel<<<(uint32_t)nm, 256, 0, stream>>>(hs, w.idx, w.h0, w.dN);

  dim3 tb(256);
  wtrans_kernel<<<dim3(DMODEL/32, DMODEL/32), tb, 0, stream>>>(w_q, w.Wqkv, DMODEL, DMODEL);
  wtrans_kernel<<<dim3(KVDIM/32,  DMODEL/32), tb, 0, stream>>>(w_k, w.Wqkv + (size_t)QDIM * DMODEL, DMODEL, KVDIM);
  wtrans_kernel<<<dim3(KVDIM/32,  DMODEL/32), tb, 0, stream>>>(w_v, w.Wqkv + (size_t)(QDIM + KVDIM) * DMODEL, DMODEL, KVDIM);
  wtrans_kernel<<<dim3(DMODEL/32, DMODEL/32), tb, 0, stream>>>(w_o, w.Wo, DMODEL, DMODEL);
  wtrans_kernel<<<dim3(DFF/32,    DMODEL/32), tb, 0, stream>>>(w_g, w.Wg, DMODEL, DFF);
  wtrans_kernel<<<dim3(DFF/32,    DMODEL/32), tb, 0, stream>>>(w_u, w.Wu, DMODEL, DFF);
  wtrans_kernel<<<dim3(DMODEL/32, DFF/32),    tb, 0, stream>>>(w_d, w.Wd, DFF, DMODEL);

  const int gy  = (int)(nm / 128);
  const int gy2 = (int)(nm / 256);
  float* outF = (float*)d_out;
  const long zs = (long)nm * DMODEL;   // partial z-stride (elements)

  for (int p = 0; p < NSTEPS; ++p) {
    const float* hprev = (p == 0) ? w.h0 : outF + (size_t)(p - 1) * DMODEL;
    const long   hstr  = (p == 0) ? DMODEL : (long)NSTEPS * DMODEL;

    rmsnorm_kernel<<<(uint32_t)nm, 256, 0, stream>>>(hprev, hstr, ln1, w.x, w.dN);

    gemm_kernel<0><<<dim3(QKVDIM/128, gy), 256, 0, stream>>>(w.x, w.Wqkv, DMODEL, w.dN,
        nullptr, 0, nullptr, 0, w.qkv, QKVDIM);

    rope_cache_kernel<<<(uint32_t)nm, 512, 0, stream>>>(w.qkv, w.kc, w.vc, p, w.dN);
    attn_kernel<<<dim3((uint32_t)nm, 8), 256, 0, stream>>>(w.qkv, w.kc, w.vc, w.o, p, w.dN);

    gemm_kernel<1><<<dim3(DMODEL/128, gy), 256, 0, stream>>>(w.o, w.Wo, DMODEL, w.dN,
        w.hattn, DMODEL, hprev, hstr, nullptr, 0);

    rmsnorm_kernel<<<(uint32_t)nm, 256, 0, stream>>>(w.hattn, DMODEL, ln2, w.x, w.dN);

    // gate: grid (64, 8) = 512 blocks -> 2 blocks/CU
    gemm256b_kernel<0><<<dim3(DFF/128, gy2, 1), 512, 0, stream>>>(w.x, w.Wg, DMODEL, DMODEL,
        w.dN, 0, w.gate, DFF, nullptr, 0);

    // up (fused silu-mul epilogue): same 512-block grid
    gemm256b_kernel<2><<<dim3(DFF/128, gy2, 1), 512, 0, stream>>>(w.x, w.Wu, DMODEL, DMODEL,
        w.dN, 0, w.gate, DFF, w.gate, DFF);

    // down: split-K=4 -> grid (16, 8, 4) = 512 blocks -> 2 blocks/CU;
    // bf16 partials overlay {h0,x,qkv,o} (dead here, rewritten next step).
    gemm256b_kernel<3><<<dim3(DMODEL/128, gy2, 4), 512, 0, stream>>>(w.gate, w.Wd, DFF, DFF/4,
        w.dN, zs, w.part, DMODEL, nullptr, 0);
    reduce_down_kernel<<<(uint32_t)nm, 256, 0, stream>>>(
        w.part, zs, w.hattn, outF + (size_t)p * DMODEL, w.dN);
  }
}

// Round 12
// 1897.070 us; speedup vs baseline: 1.1818x; 1.1818x over previous
//
#include <hip/hip_runtime.h>
#include <hip/hip_bf16.h>
#include <stdint.h>

#define DMODEL 2048
#define QDIM   2048
#define KVDIM  512
#define QKVDIM 3072
#define DFF    8192
#define NSTEPS 5

typedef __bf16 bf16_t;
typedef __attribute__((ext_vector_type(8))) __bf16 bf16x8;
typedef __attribute__((ext_vector_type(4))) float f32x4;

// global -> LDS direct DMA, 16B per lane. LDS dest is wave-uniform base;
// HW writes lane i at base + i*16. Requires linear (unpadded) LDS layout.
#define GLL16(g, l)                                                         \
  __builtin_amdgcn_global_load_lds(                                          \
      (const __attribute__((address_space(1))) void*)(g),                    \
      (__attribute__((address_space(3))) void*)(l), 16, 0, 0)

#define MFMA_BF16 __builtin_amdgcn_mfma_f32_16x16x32_bf16

__device__ __forceinline__ float wave_sum(float v) {
#pragma unroll
  for (int o = 32; o > 0; o >>= 1) v += __shfl_xor(v, o, 64);
  return v;
}

// ---------------- index building (handles int32 or int64 length arrays) ----
__global__ void build_idx_kernel(const int* __restrict__ seq, const int* __restrict__ inst,
                                 int B, int* __restrict__ idx, int* __restrict__ dN, int nmax) {
  __shared__ int sbase[64], soff[64], scnt[64], snb;
  if (threadIdx.x == 0) {
    bool is64 = (B >= 2);
    for (int i = 0; i < B && is64; ++i) {
      if (i & 1) { if (seq[i] != 0 || inst[i] != 0) is64 = false; }
      else       { if (seq[i] == 0) is64 = false; }
    }
    int off = 0, row = 0, nb = (B < 64 ? B : 64);
    for (int b = 0; b < nb; ++b) {
      int s = is64 ? seq[2 * b] : seq[b];
      int i = is64 ? inst[2 * b] : inst[b];
      sbase[b] = row; soff[b] = off + i - 1; scnt[b] = s - i;
      row += s - i; off += s;
    }
    snb = nb;
    *dN = row < nmax ? row : nmax;
  }
  __syncthreads();
  int nb = snb;
  for (int b = 0; b < nb; ++b) {
    int cnt = scnt[b], base = sbase[b], o0 = soff[b];
    for (int t = threadIdx.x; t < cnt; t += blockDim.x) {
      int r = base + t;
      if (r < nmax) idx[r] = o0 + t;
    }
  }
}

// ---------------- gather rows into h0 (fp32) -------------------------------
__global__ __launch_bounds__(256)
void gather_kernel(const float* __restrict__ hs, const int* __restrict__ idx,
                   float* __restrict__ h0, const int* __restrict__ dN) {
  int r = blockIdx.x; if (r >= *dN) return;
  const float4* in = (const float4*)(hs + (size_t)idx[r] * DMODEL);
  float4* out = (float4*)(h0 + (size_t)r * DMODEL);
  out[threadIdx.x]       = in[threadIdx.x];
  out[threadIdx.x + 256] = in[threadIdx.x + 256];
}

// ---------------- fp32 -> bf16 transpose of a weight matrix ----------------
// W is [K][Nc] row-major fp32, Wt is [Nc][K] row-major bf16
__global__ __launch_bounds__(256)
void wtrans_kernel(const float* __restrict__ W, bf16_t* __restrict__ Wt, int K, int Nc) {
  __shared__ float tile[32][33];
  int c0 = blockIdx.x * 32, k0 = blockIdx.y * 32;
  int tx = threadIdx.x & 31, ty = threadIdx.x >> 5;
#pragma unroll
  for (int yy = 0; yy < 4; ++yy)
    tile[ty + 8 * yy][tx] = W[(size_t)(k0 + ty + 8 * yy) * Nc + c0 + tx];
  __syncthreads();
#pragma unroll
  for (int yy = 0; yy < 4; ++yy)
    Wt[(size_t)(c0 + ty + 8 * yy) * K + k0 + tx] = (bf16_t)tile[tx][ty + 8 * yy];
}

// ---------------- RMSNorm: fp32 row -> bf16 row (only used at p=0) ---------
__global__ __launch_bounds__(256)
void rmsnorm_kernel(const float* __restrict__ h, long hstride, const float* __restrict__ w,
                    bf16_t* __restrict__ x, const int* __restrict__ dN) {
  int r = blockIdx.x; if (r >= *dN) return;
  const float* row = h + (size_t)r * hstride;
  int t = threadIdx.x;
  float4 v0 = ((const float4*)row)[2 * t];
  float4 v1 = ((const float4*)row)[2 * t + 1];
  float ss = v0.x*v0.x + v0.y*v0.y + v0.z*v0.z + v0.w*v0.w
           + v1.x*v1.x + v1.y*v1.y + v1.z*v1.z + v1.w*v1.w;
  ss = wave_sum(ss);
  __shared__ float part[4];
  if ((t & 63) == 0) part[t >> 6] = ss;
  __syncthreads();
  float inv = rsqrtf((part[0] + part[1] + part[2] + part[3]) * (1.0f / DMODEL) + 1e-6f);
  const float4* wv = (const float4*)w;
  float4 w0 = wv[2 * t], w1 = wv[2 * t + 1];
  union { bf16_t b[8]; uint4 q; } u;
  u.b[0] = (bf16_t)(v0.x * inv * w0.x);
  u.b[1] = (bf16_t)(v0.y * inv * w0.y);
  u.b[2] = (bf16_t)(v0.z * inv * w0.z);
  u.b[3] = (bf16_t)(v0.w * inv * w0.w);
  u.b[4] = (bf16_t)(v1.x * inv * w1.x);
  u.b[5] = (bf16_t)(v1.y * inv * w1.y);
  u.b[6] = (bf16_t)(v1.z * inv * w1.z);
  u.b[7] = (bf16_t)(v1.w * inv * w1.w);
  *(uint4*)(x + (size_t)r * DMODEL + t * 8) = u.q;
}

// ---------------- RoPE(k at pos p) + append k,v to cache -------------------
__global__ __launch_bounds__(512)
void rope_cache_kernel(const bf16_t* __restrict__ qkv, bf16_t* __restrict__ kc,
                       bf16_t* __restrict__ vc, int p, const int* __restrict__ dN) {
  int r = blockIdx.x; if (r >= *dN) return;
  int d = threadIdx.x;           // 0..511
  int e = d & 63, fi = e & 31;
  size_t qb = (size_t)r * QKVDIM;
  float k  = (float)qkv[qb + QDIM + d];
  float kp = (float)qkv[qb + QDIM + (d ^ 32)];
  float ang = (float)p * expf((float)fi * -0.28782313662425576f); // -ln(1e4)/32
  float cv, sv; sincosf(ang, &sv, &cv);
  float kr = k * cv + ((e < 32) ? -kp : kp) * sv;
  size_t cb = ((size_t)r * NSTEPS + p) * KVDIM + d;
  kc[cb] = (bf16_t)kr;
  vc[cb] = qkv[qb + QDIM + KVDIM + d];
}

// ---------------- attention at position p (one wave per row,head) ----------
__global__ __launch_bounds__(256)
void attn_kernel(const bf16_t* __restrict__ qkv, const bf16_t* __restrict__ kc,
                 const bf16_t* __restrict__ vc, bf16_t* __restrict__ o,
                 int p, const int* __restrict__ dN) {
  int r = blockIdx.x; if (r >= *dN) return;
  int wid = threadIdx.x >> 6, lane = threadIdx.x & 63;
  int head = blockIdx.y * 4 + wid;
  int kh = head >> 2;
  float q = (float)qkv[(size_t)r * QKVDIM + head * 64 + lane];
  int fi = lane & 31;
  float ang = (float)p * expf((float)fi * -0.28782313662425576f);
  float cv, sv; sincosf(ang, &sv, &cv);
  float qp = __shfl_xor(q, 32, 64);
  float qr = q * cv + ((lane < 32) ? -qp : qp) * sv;
  size_t cbase = (size_t)r * NSTEPS * KVDIM + kh * 64 + lane;
  float s[NSTEPS];
#pragma unroll
  for (int j = 0; j < NSTEPS; ++j) {
    s[j] = -1e30f;
    if (j <= p) {
      float kj = (float)kc[cbase + (size_t)j * KVDIM];
      s[j] = wave_sum(qr * kj) * 0.125f;
    }
  }
  float m = s[0];
#pragma unroll
  for (int j = 1; j < NSTEPS; ++j) m = fmaxf(m, s[j]);
  float aw[NSTEPS]; float den = 0.f;
#pragma unroll
  for (int j = 0; j < NSTEPS; ++j) { aw[j] = (j <= p) ? expf(s[j] - m) : 0.f; den += aw[j]; }
  float oa = 0.f;
#pragma unroll
  for (int j = 0; j < NSTEPS; ++j)
    if (j <= p) oa += aw[j] * (float)vc[cbase + (size_t)j * KVDIM];
  o[(size_t)r * QDIM + head * 64 + lane] = (bf16_t)(oa / den);
}

// ---------------- 256x256 GEMM, BK=64, counted vmcnt (round-10 config) -----
// 8 waves (2M x 4N), per-wave out 128x64 (acc[8][4]). LDS 128 KiB dynamic.
// One barrier per phase; lgkmcnt(0) BEFORE barrier so barrier-crossing
// certifies all waves' phase reads complete (WAR-safe staging, see r10).
// Stage targets: ph1->(T+1).A kh1 | ph2->(T+1).B kh1 | ph3->(T+2).A kh0 |
// ph4->(T+2).B kh0. vmcnt(8) at ph2/ph4 retires the next-needed half-pair.
// Tail: vmcnt(4) at nt-2, vmcnt(0) at nt-1. Swizzle slot^=(row>>1)&3 both
// sides (measured conflict-free). Requires nt >= 2.
// MODE 0: outb = bf16(acc); MODE 2: outb = bf16(silu(gateb)*acc);
// MODE 3: bf16 partial at outb + blockIdx.z * zstride.
template <int MODE>
__global__ __launch_bounds__(512)
void gemm256_kernel(const bf16_t* __restrict__ A, const bf16_t* __restrict__ Bt,
                    int krow, int kchunk, const int* __restrict__ dN,
                    long zstride,
                    bf16_t* __restrict__ outb, long obstride,
                    const bf16_t* __restrict__ gateb, long gstride) {
  const int N = *dN;
  const int brow = blockIdx.y * 256, bcol = blockIdx.x * 256;
  if (brow >= N) return;
  const size_t koff = (size_t)blockIdx.z * kchunk;

  extern __shared__ __align__(16) bf16_t lds[];
  bf16_t* As = lds;             // elems: buf*16384 + kh*8192 + row*32 + slot*8
  bf16_t* Bs = lds + 32768;

  const int t = threadIdx.x;
  const int lane = t & 63, wid = t >> 6;        // 8 waves
  const int wm = wid >> 2, wn = wid & 3;        // 2 x 4
  const int hi = lane >> 4, lo = lane & 15;

  const int swsrc = ((lane & 3) ^ ((lane >> 3) & 3)) << 3;
  const size_t aoffl = (size_t)(brow + (lane >> 2)) * krow + koff + swsrc;
  const size_t boffl = (size_t)(bcol + (lane >> 2)) * krow + koff + swsrc;
  const size_t chk0 = (size_t)(wid * 32) * krow;
  const size_t chk1 = (size_t)(wid * 32 + 16) * krow;
  const int lst0 = wid * 1024;
  const int lst1 = wid * 1024 + 512;

  const int rsl = (hi ^ ((lo >> 1) & 3)) * 8;
  const int abase = (wm * 128 + lo) * 32 + rsl;   // + m*512 (+kh*8192 +buf)
  const int bbase = (wn * 64 + lo) * 32 + rsl;    // + n*512

  f32x4 acc[8][4] = {};
  const int nt = kchunk >> 6;                     // K-tiles of 64

#define STG_A(T, kh) do {                                        \
    const bf16_t* g_ = A + aoffl + (size_t)(T) * 64 + (kh) * 32; \
    bf16_t* l_ = As + (((T) & 1) << 14) + (kh) * 8192;           \
    GLL16(g_ + chk0, l_ + lst0);                                 \
    GLL16(g_ + chk1, l_ + lst1);                                 \
  } while (0)
#define STG_B(T, kh) do {                                        \
    const bf16_t* g_ = Bt + boffl + (size_t)(T) * 64 + (kh) * 32;\
    bf16_t* l_ = Bs + (((T) & 1) << 14) + (kh) * 8192;           \
    GLL16(g_ + chk0, l_ + lst0);                                 \
    GLL16(g_ + chk1, l_ + lst1);                                 \
  } while (0)

  STG_A(0, 0); STG_B(0, 0); STG_A(0, 1); STG_B(0, 1);
  if (nt > 1) {
    STG_A(1, 0); STG_B(1, 0);
    asm volatile("s_waitcnt vmcnt(8)" ::: "memory");
  } else {
    asm volatile("s_waitcnt vmcnt(4)" ::: "memory");
  }
  __builtin_amdgcn_s_barrier();

  for (int T = 0; T < nt; ++T) {
    const int buf = (T & 1) << 14;
    bf16x8 af[8], b0, b1;
    // ---------- phase 1: (kh0, n=0,1); stage (T+1).A kh1 ----------
#pragma unroll
    for (int m = 0; m < 8; ++m)
      af[m] = *(const bf16x8*)(As + buf + abase + m * 512);
    b0 = *(const bf16x8*)(Bs + buf + bbase);
    b1 = *(const bf16x8*)(Bs + buf + bbase + 512);
    if (T + 1 < nt) STG_A(T + 1, 1);
    asm volatile("s_waitcnt lgkmcnt(0)" ::: "memory");
    __builtin_amdgcn_s_barrier();
    __builtin_amdgcn_s_setprio(1);
#pragma unroll
    for (int m = 0; m < 8; ++m) {
      acc[m][0] = MFMA_BF16(af[m], b0, acc[m][0], 0, 0, 0);
      acc[m][1] = MFMA_BF16(af[m], b1, acc[m][1], 0, 0, 0);
    }
    __builtin_amdgcn_s_setprio(0);
    // ---------- phase 2: (kh0, n=2,3); stage (T+1).B kh1; vmcnt ----------
    b0 = *(const bf16x8*)(Bs + buf + bbase + 1024);
    b1 = *(const bf16x8*)(Bs + buf + bbase + 1536);
    if (T + 1 < nt) STG_B(T + 1, 1);
    if (T < nt - 1) asm volatile("s_waitcnt vmcnt(8) lgkmcnt(0)" ::: "memory");
    else            asm volatile("s_waitcnt vmcnt(0) lgkmcnt(0)" ::: "memory");
    __builtin_amdgcn_s_barrier();
    __builtin_amdgcn_s_setprio(1);
#pragma unroll
    for (int m = 0; m < 8; ++m) {
      acc[m][2] = MFMA_BF16(af[m], b0, acc[m][2], 0, 0, 0);
      acc[m][3] = MFMA_BF16(af[m], b1, acc[m][3], 0, 0, 0);
    }
    __builtin_amdgcn_s_setprio(0);
    // ---------- phase 3: (kh1, n=0,1); stage (T+2).A kh0 ----------
#pragma unroll
    for (int m = 0; m < 8; ++m)
      af[m] = *(const bf16x8*)(As + buf + 8192 + abase + m * 512);
    b0 = *(const bf16x8*)(Bs + buf + 8192 + bbase);
    b1 = *(const bf16x8*)(Bs + buf + 8192 + bbase + 512);
    if (T + 2 < nt) STG_A(T + 2, 0);
    asm volatile("s_waitcnt lgkmcnt(0)" ::: "memory");
    __builtin_amdgcn_s_barrier();
    __builtin_amdgcn_s_setprio(1);
#pragma unroll
    for (int m = 0; m < 8; ++m) {
      acc[m][0] = MFMA_BF16(af[m], b0, acc[m][0], 0, 0, 0);
      acc[m][1] = MFMA_BF16(af[m], b1, acc[m][1], 0, 0, 0);
    }
    __builtin_amdgcn_s_setprio(0);
    // ---------- phase 4: (kh1, n=2,3); stage (T+2).B kh0; vmcnt ----------
    b0 = *(const bf16x8*)(Bs + buf + 8192 + bbase + 1024);
    b1 = *(const bf16x8*)(Bs + buf + 8192 + bbase + 1536);
    if (T + 2 < nt) STG_B(T + 2, 0);
    if (T < nt - 2)       asm volatile("s_waitcnt vmcnt(8) lgkmcnt(0)" ::: "memory");
    else if (T == nt - 2) asm volatile("s_waitcnt vmcnt(4) lgkmcnt(0)" ::: "memory");
    else                  asm volatile("s_waitcnt vmcnt(0) lgkmcnt(0)" ::: "memory");
    __builtin_amdgcn_s_barrier();
    __builtin_amdgcn_s_setprio(1);
#pragma unroll
    for (int m = 0; m < 8; ++m) {
      acc[m][2] = MFMA_BF16(af[m], b0, acc[m][2], 0, 0, 0);
      acc[m][3] = MFMA_BF16(af[m], b1, acc[m][3], 0, 0, 0);
    }
    __builtin_amdgcn_s_setprio(0);
  }
#undef STG_A
#undef STG_B

  const int rbase = brow + wm * 128 + hi * 4;
  const int cbase = bcol + wn * 64 + lo;
  bf16_t* pb = (MODE == 3) ? outb + (size_t)blockIdx.z * zstride : outb;
#pragma unroll
  for (int m = 0; m < 8; ++m) {
#pragma unroll
    for (int n = 0; n < 4; ++n) {
      const int col = cbase + n * 16;
#pragma unroll
      for (int j = 0; j < 4; ++j) {
        const int row = rbase + m * 16 + j;
        if (row < N) {
          float v = acc[m][n][j];
          if (MODE == 2) {
            float g = (float)gateb[(size_t)row * gstride + col];
            float sg = g / (1.0f + expf(-g));
            pb[(size_t)row * obstride + col] = (bf16_t)(sg * v);
          } else {
            pb[(size_t)row * obstride + col] = (bf16_t)v;
          }
        }
      }
    }
  }
}

// ---------------- split-K reduce for QKV (NZ=2, bf16 out) ------------------
__global__ __launch_bounds__(384)
void reduce_qkv_kernel(const bf16_t* __restrict__ part, long zstride,
                       bf16_t* __restrict__ out, const int* __restrict__ dN) {
  int r = blockIdx.x; if (r >= *dN) return;
  const int c = threadIdx.x * 8;                // 384*8 == QKVDIM exactly
  const bf16x8 a = *(const bf16x8*)(part + (size_t)r * QKVDIM + c);
  const bf16x8 b = *(const bf16x8*)(part + zstride + (size_t)r * QKVDIM + c);
  union { bf16_t v[8]; uint4 q; } u;
#pragma unroll
  for (int j = 0; j < 8; ++j) u.v[j] = (bf16_t)((float)a[j] + (float)b[j]);
  *(uint4*)(out + (size_t)r * QKVDIM + c) = u.q;
}

// ---------------- split-K reduce + residual + optional fused RMSNorm -------
// out[r] (stride ostride) = res[r] (stride rstride) + sum_{z<NZ} part[z][r]
// if x != nullptr: x[r] = bf16(rmsnorm(out[r]) * lnw)   (DMODEL cols)
template <int NZ>
__global__ __launch_bounds__(256)
void reduce_norm_kernel(const bf16_t* __restrict__ part, long zstride,
                        const float* __restrict__ res, long rstride,
                        float* __restrict__ out, long ostride,
                        bf16_t* __restrict__ x, const float* __restrict__ lnw,
                        const int* __restrict__ dN) {
  int r = blockIdx.x; if (r >= *dN) return;
  const int c = threadIdx.x * 8;                // 256*8 == DMODEL exactly
  const float* rv = res + (size_t)r * rstride + c;
  float s[8];
#pragma unroll
  for (int j = 0; j < 8; ++j) s[j] = rv[j];
#pragma unroll
  for (int z = 0; z < NZ; ++z) {
    const bf16x8 v = *(const bf16x8*)(part + (size_t)z * zstride + (size_t)r * DMODEL + c);
#pragma unroll
    for (int j = 0; j < 8; ++j) s[j] += (float)v[j];
  }
  float* o = out + (size_t)r * ostride + c;
#pragma unroll
  for (int j = 0; j < 8; ++j) o[j] = s[j];
  if (x) {
    float ss = 0.f;
#pragma unroll
    for (int j = 0; j < 8; ++j) ss += s[j] * s[j];
    ss = wave_sum(ss);
    __shared__ float ps[4];
    if ((threadIdx.x & 63) == 0) ps[threadIdx.x >> 6] = ss;
    __syncthreads();
    float inv = rsqrtf((ps[0] + ps[1] + ps[2] + ps[3]) * (1.0f / DMODEL) + 1e-6f);
    union { bf16_t b[8]; uint4 q; } u;
#pragma unroll
    for (int j = 0; j < 8; ++j) u.b[j] = (bf16_t)(s[j] * inv * lnw[c + j]);
    *(uint4*)(x + (size_t)r * DMODEL + c) = u.q;
  }
}

// ---------------------------------------------------------------------------
extern "C" void kernel_launch(void* const* d_in, const int* in_sizes, int n_in,
                              void* d_out, int out_size, void* d_ws, size_t ws_size,
                              hipStream_t stream) {
  const float* hs  = (const float*)d_in[0];
  const int*   seq = (const int*)d_in[1];
  const int*   ins = (const int*)d_in[2];
  const float* w_q = (const float*)d_in[3];
  const float* w_k = (const float*)d_in[4];
  const float* w_v = (const float*)d_in[5];
  const float* w_o = (const float*)d_in[6];
  const float* ln1 = (const float*)d_in[7];
  const float* ln2 = (const float*)d_in[8];
  const float* w_g = (const float*)d_in[9];
  const float* w_u = (const float*)d_in[10];
  const float* w_d = (const float*)d_in[11];
  const int  B     = in_sizes[1];
  const long total = (long)in_sizes[0] / DMODEL;

  const size_t WQKV_E = (size_t)QKVDIM * DMODEL;
  const size_t WO_E   = (size_t)DMODEL * DMODEL;
  const size_t WG_E   = (size_t)DFF * DMODEL;

  struct WS {
    int* dN; int* idx;
    bf16_t *Wqkv, *Wo, *Wg, *Wu, *Wd;
    bf16_t* kc; bf16_t* vc; float* hattn; bf16_t* gate;
    bf16_t* qkv; bf16_t* o; float* h0; bf16_t* x;     // tail: {qkv,o,h0} dead
    bf16_t* part;                                      // overlays {qkv,o,h0}
    size_t bytes;
  };
  char* base = (char*)d_ws;
  auto mk = [&](long nm) {
    WS w; size_t o = 0;
    auto alloc = [&](size_t b) { char* p = base + o; o = (o + b + 255) & ~(size_t)255; return p; };
    w.dN    = (int*)alloc(4);
    w.idx   = (int*)alloc((size_t)nm * 4);
    w.Wqkv  = (bf16_t*)alloc(WQKV_E * 2);
    w.Wo    = (bf16_t*)alloc(WO_E * 2);
    w.Wg    = (bf16_t*)alloc(WG_E * 2);
    w.Wu    = (bf16_t*)alloc(WG_E * 2);
    w.Wd    = (bf16_t*)alloc(WG_E * 2);
    w.kc    = (bf16_t*)alloc((size_t)nm * NSTEPS * KVDIM * 2);
    w.vc    = (bf16_t*)alloc((size_t)nm * NSTEPS * KVDIM * 2);
    w.hattn = (float*)alloc((size_t)nm * DMODEL * 4);
    w.gate  = (bf16_t*)alloc((size_t)nm * DFF * 2);
    // tail {qkv,o,h0} = nm*(6144+4096+8192)B = nm*18432B, all dead during
    // down-GEMM; its split-K partials (4*nm*DMODEL*2 = nm*16384B) overlay it.
    // x sits AFTER the overlay so fused reduces may write it safely.
    w.qkv   = (bf16_t*)alloc((size_t)nm * QKVDIM * 2);
    w.o     = (bf16_t*)alloc((size_t)nm * DMODEL * 2);
    w.h0    = (float*)alloc((size_t)nm * DMODEL * 4);
    w.x     = (bf16_t*)alloc((size_t)nm * DMODEL * 2);
    w.part  = (bf16_t*)w.qkv;
    w.bytes = o;
    return w;
  };
  long nm = ((total + 255) / 256) * 256;
  WS w = mk(nm);
  while (w.bytes > ws_size && nm > 256) { nm -= 256; w = mk(nm); }

  build_idx_kernel<<<1, 512, 0, stream>>>(seq, ins, B, w.idx, w.dN, (int)nm);
  gather_kernel<<<(uint32_t)nm, 256, 0, stream>>>(hs, w.idx, w.h0, w.dN);

  dim3 tb(256);
  wtrans_kernel<<<dim3(DMODEL/32, DMODEL/32), tb, 0, stream>>>(w_q, w.Wqkv, DMODEL, DMODEL);
  wtrans_kernel<<<dim3(KVDIM/32,  DMODEL/32), tb, 0, stream>>>(w_k, w.Wqkv + (size_t)QDIM * DMODEL, DMODEL, KVDIM);
  wtrans_kernel<<<dim3(KVDIM/32,  DMODEL/32), tb, 0, stream>>>(w_v, w.Wqkv + (size_t)(QDIM + KVDIM) * DMODEL, DMODEL, KVDIM);
  wtrans_kernel<<<dim3(DMODEL/32, DMODEL/32), tb, 0, stream>>>(w_o, w.Wo, DMODEL, DMODEL);
  wtrans_kernel<<<dim3(DFF/32,    DMODEL/32), tb, 0, stream>>>(w_g, w.Wg, DMODEL, DFF);
  wtrans_kernel<<<dim3(DFF/32,    DMODEL/32), tb, 0, stream>>>(w_u, w.Wu, DMODEL, DFF);
  wtrans_kernel<<<dim3(DMODEL/32, DFF/32),    tb, 0, stream>>>(w_d, w.Wd, DFF, DMODEL);

  const int gy2 = (int)(nm / 256);
  const uint32_t LDSB = 131072;        // 128 KiB dynamic LDS for gemm256
  float* outF = (float*)d_out;
  const long zsD = (long)nm * DMODEL;   // partial z-stride, DMODEL cols
  const long zsQ = (long)nm * QKVDIM;   // partial z-stride, QKVDIM cols

  for (int p = 0; p < NSTEPS; ++p) {
    const float* hprev = (p == 0) ? w.h0 : outF + (size_t)(p - 1) * DMODEL;
    const long   hstr  = (p == 0) ? DMODEL : (long)NSTEPS * DMODEL;

    // ln1 for p>0 is fused into the previous step's reduce_norm (down).
    if (p == 0)
      rmsnorm_kernel<<<(uint32_t)nm, 256, 0, stream>>>(hprev, hstr, ln1, w.x, w.dN);

    // QKV: split-K=2 (grid 12 x gy2 x 2 = 192 blocks, nt=16); bf16 partials
    // in w.gate (dead between down-reduce and gate-GEMM), then reduce.
    gemm256_kernel<3><<<dim3(QKVDIM/256, gy2, 2), 512, LDSB, stream>>>(
        w.x, w.Wqkv, DMODEL, DMODEL/2, w.dN, zsQ, w.gate, QKVDIM, nullptr, 0);
    reduce_qkv_kernel<<<(uint32_t)nm, 384, 0, stream>>>(w.gate, zsQ, w.qkv, w.dN);

    rope_cache_kernel<<<(uint32_t)nm, 512, 0, stream>>>(w.qkv, w.kc, w.vc, p, w.dN);
    attn_kernel<<<dim3((uint32_t)nm, 8), 256, 0, stream>>>(w.qkv, w.kc, w.vc, w.o, p, w.dN);

    // Wo: split-K=4 (grid 8 x gy2 x 4 = 256 blocks, nt=8); partials in
    // w.gate; fused reduce adds residual hprev AND applies ln2 -> x.
    gemm256_kernel<3><<<dim3(DMODEL/256, gy2, 4), 512, LDSB, stream>>>(
        w.o, w.Wo, DMODEL, DMODEL/4, w.dN, zsD, w.gate, DMODEL, nullptr, 0);
    reduce_norm_kernel<4><<<(uint32_t)nm, 256, 0, stream>>>(
        w.gate, zsD, hprev, hstr, w.hattn, DMODEL, w.x, ln2, w.dN);

    // gate / up (round-10 config: full-K gemm256, grid 32 x gy2 = 256 blocks)
    gemm256_kernel<0><<<dim3(DFF/256, gy2, 1), 512, LDSB, stream>>>(
        w.x, w.Wg, DMODEL, DMODEL, w.dN, 0, w.gate, DFF, nullptr, 0);
    gemm256_kernel<2><<<dim3(DFF/256, gy2, 1), 512, LDSB, stream>>>(
        w.x, w.Wu, DMODEL, DMODEL, w.dN, 0, w.gate, DFF, w.gate, DFF);

    // down: split-K=4 -> partials overlay {qkv,o,h0} (dead here); fused
    // reduce adds hattn residual, writes outF[p], and (p<last) ln1 -> x.
    gemm256_kernel<3><<<dim3(DMODEL/256, gy2, 4), 512, LDSB, stream>>>(
        w.gate, w.Wd, DFF, DFF/4, w.dN, zsD, w.part, DMODEL, nullptr, 0);
    reduce_norm_kernel<4><<<(uint32_t)nm, 256, 0, stream>>>(
        w.part, zsD, w.hattn, DMODEL, outF + (size_t)p * DMODEL, (long)NSTEPS * DMODEL,
        (p + 1 < NSTEPS) ? w.x : nullptr, ln1, w.dN);
  }
}

// Round 14
// 1837.846 us; speedup vs baseline: 1.2199x; 1.0322x over previous
//
#include <hip/hip_runtime.h>
#include <hip/hip_bf16.h>
#include <stdint.h>

#define DMODEL 2048
#define QDIM   2048
#define KVDIM  512
#define QKVDIM 3072
#define DFF    8192
#define NSTEPS 5

typedef __bf16 bf16_t;
typedef __attribute__((ext_vector_type(8))) __bf16 bf16x8;
typedef __attribute__((ext_vector_type(4))) float f32x4;

// global -> LDS direct DMA, 16B per lane. LDS dest is wave-uniform base;
// HW writes lane i at base + i*16. Requires linear (unpadded) LDS layout.
#define GLL16(g, l)                                                         \
  __builtin_amdgcn_global_load_lds(                                          \
      (const __attribute__((address_space(1))) void*)(g),                    \
      (__attribute__((address_space(3))) void*)(l), 16, 0, 0)

#define MFMA_BF16 __builtin_amdgcn_mfma_f32_16x16x32_bf16

__device__ __forceinline__ float wave_sum(float v) {
#pragma unroll
  for (int o = 32; o > 0; o >>= 1) v += __shfl_xor(v, o, 64);
  return v;
}

// ---------------- index building (handles int32 or int64 length arrays) ----
__global__ void build_idx_kernel(const int* __restrict__ seq, const int* __restrict__ inst,
                                 int B, int* __restrict__ idx, int* __restrict__ dN, int nmax) {
  __shared__ int sbase[64], soff[64], scnt[64], snb;
  if (threadIdx.x == 0) {
    bool is64 = (B >= 2);
    for (int i = 0; i < B && is64; ++i) {
      if (i & 1) { if (seq[i] != 0 || inst[i] != 0) is64 = false; }
      else       { if (seq[i] == 0) is64 = false; }
    }
    int off = 0, row = 0, nb = (B < 64 ? B : 64);
    for (int b = 0; b < nb; ++b) {
      int s = is64 ? seq[2 * b] : seq[b];
      int i = is64 ? inst[2 * b] : inst[b];
      sbase[b] = row; soff[b] = off + i - 1; scnt[b] = s - i;
      row += s - i; off += s;
    }
    snb = nb;
    *dN = row < nmax ? row : nmax;
  }
  __syncthreads();
  int nb = snb;
  for (int b = 0; b < nb; ++b) {
    int cnt = scnt[b], base = sbase[b], o0 = soff[b];
    for (int t = threadIdx.x; t < cnt; t += blockDim.x) {
      int r = base + t;
      if (r < nmax) idx[r] = o0 + t;
    }
  }
}

// ---------------- gather rows into h0 (fp32) -------------------------------
__global__ __launch_bounds__(256)
void gather_kernel(const float* __restrict__ hs, const int* __restrict__ idx,
                   float* __restrict__ h0, const int* __restrict__ dN) {
  int r = blockIdx.x; if (r >= *dN) return;
  const float4* in = (const float4*)(hs + (size_t)idx[r] * DMODEL);
  float4* out = (float4*)(h0 + (size_t)r * DMODEL);
  out[threadIdx.x]       = in[threadIdx.x];
  out[threadIdx.x + 256] = in[threadIdx.x + 256];
}

// ---------------- fp32 -> bf16 transpose of a weight matrix ----------------
// W is [K][Nc] row-major fp32, Wt is [Nc][K] row-major bf16
__global__ __launch_bounds__(256)
void wtrans_kernel(const float* __restrict__ W, bf16_t* __restrict__ Wt, int K, int Nc) {
  __shared__ float tile[32][33];
  int c0 = blockIdx.x * 32, k0 = blockIdx.y * 32;
  int tx = threadIdx.x & 31, ty = threadIdx.x >> 5;
#pragma unroll
  for (int yy = 0; yy < 4; ++yy)
    tile[ty + 8 * yy][tx] = W[(size_t)(k0 + ty + 8 * yy) * Nc + c0 + tx];
  __syncthreads();
#pragma unroll
  for (int yy = 0; yy < 4; ++yy)
    Wt[(size_t)(c0 + ty + 8 * yy) * K + k0 + tx] = (bf16_t)tile[tx][ty + 8 * yy];
}

// ---------------- RMSNorm: fp32 row -> bf16 row (only used at p=0) ---------
__global__ __launch_bounds__(256)
void rmsnorm_kernel(const float* __restrict__ h, long hstride, const float* __restrict__ w,
                    bf16_t* __restrict__ x, const int* __restrict__ dN) {
  int r = blockIdx.x; if (r >= *dN) return;
  const float* row = h + (size_t)r * hstride;
  int t = threadIdx.x;
  float4 v0 = ((const float4*)row)[2 * t];
  float4 v1 = ((const float4*)row)[2 * t + 1];
  float ss = v0.x*v0.x + v0.y*v0.y + v0.z*v0.z + v0.w*v0.w
           + v1.x*v1.x + v1.y*v1.y + v1.z*v1.z + v1.w*v1.w;
  ss = wave_sum(ss);
  __shared__ float part[4];
  if ((t & 63) == 0) part[t >> 6] = ss;
  __syncthreads();
  float inv = rsqrtf((part[0] + part[1] + part[2] + part[3]) * (1.0f / DMODEL) + 1e-6f);
  const float4* wv = (const float4*)w;
  float4 w0 = wv[2 * t], w1 = wv[2 * t + 1];
  union { bf16_t b[8]; uint4 q; } u;
  u.b[0] = (bf16_t)(v0.x * inv * w0.x);
  u.b[1] = (bf16_t)(v0.y * inv * w0.y);
  u.b[2] = (bf16_t)(v0.z * inv * w0.z);
  u.b[3] = (bf16_t)(v0.w * inv * w0.w);
  u.b[4] = (bf16_t)(v1.x * inv * w1.x);
  u.b[5] = (bf16_t)(v1.y * inv * w1.y);
  u.b[6] = (bf16_t)(v1.z * inv * w1.z);
  u.b[7] = (bf16_t)(v1.w * inv * w1.w);
  *(uint4*)(x + (size_t)r * DMODEL + t * 8) = u.q;
}

// ---------------- fused attention at position p ----------------------------
// Reads the QKV split-K=2 bf16 partials directly (fp32 sum in-register),
// applies RoPE(p) to q and to k(p), writes k(p)/v(p) to the cache (wave 0 —
// block (r, kh) is the unique owner), and computes attention with j == p
// served from registers. Replaces reduce_qkv + rope_cache + attn.
__global__ __launch_bounds__(256)
void attn_fused_kernel(const bf16_t* __restrict__ part, long zstride,
                       bf16_t* __restrict__ kc, bf16_t* __restrict__ vc,
                       bf16_t* __restrict__ o, int p, const int* __restrict__ dN) {
  int r = blockIdx.x; if (r >= *dN) return;
  int wid = threadIdx.x >> 6, lane = threadIdx.x & 63;
  int kh = blockIdx.y;                 // kv head 0..7
  int head = kh * 4 + wid;             // q head (4 q-heads share this kv head)
  size_t qb = (size_t)r * QKVDIM;

  int fi = lane & 31;
  float ang = (float)p * expf((float)fi * -0.28782313662425576f); // -ln(1e4)/32
  float cv, sv; sincosf(ang, &sv, &cv);

  // q = partial0 + partial1, then RoPE
  size_t qo = qb + (size_t)head * 64 + lane;
  float q = (float)part[qo] + (float)part[zstride + qo];
  float qp = __shfl_xor(q, 32, 64);
  float qr = q * cv + ((lane < 32) ? -qp : qp) * sv;

  // k(p), v(p) from partials; RoPE k
  size_t kb = qb + QDIM + (size_t)kh * 64 + lane;
  float kraw = (float)part[kb] + (float)part[zstride + kb];
  float kp_ = __shfl_xor(kraw, 32, 64);
  float kr = kraw * cv + ((lane < 32) ? -kp_ : kp_) * sv;
  size_t vb = kb + KVDIM;
  float vnew = (float)part[vb] + (float)part[zstride + vb];

  size_t cbase = (size_t)r * NSTEPS * KVDIM + (size_t)kh * 64 + lane;
  if (wid == 0) {
    kc[cbase + (size_t)p * KVDIM] = (bf16_t)kr;
    vc[cbase + (size_t)p * KVDIM] = (bf16_t)vnew;
  }

  float s[NSTEPS];
#pragma unroll
  for (int j = 0; j < NSTEPS; ++j) {
    s[j] = -1e30f;
    if (j < p) {
      float kj = (float)kc[cbase + (size_t)j * KVDIM];
      s[j] = wave_sum(qr * kj) * 0.125f;
    } else if (j == p) {
      s[j] = wave_sum(qr * (float)(bf16_t)kr) * 0.125f;  // match cached bf16
    }
  }
  float m = s[0];
#pragma unroll
  for (int j = 1; j < NSTEPS; ++j) m = fmaxf(m, s[j]);
  float aw[NSTEPS]; float den = 0.f;
#pragma unroll
  for (int j = 0; j < NSTEPS; ++j) { aw[j] = (j <= p) ? expf(s[j] - m) : 0.f; den += aw[j]; }
  float oa = 0.f;
#pragma unroll
  for (int j = 0; j < NSTEPS; ++j) {
    if (j < p)       oa += aw[j] * (float)vc[cbase + (size_t)j * KVDIM];
    else if (j == p) oa += aw[j] * (float)(bf16_t)vnew;
  }
  o[(size_t)r * QDIM + (size_t)head * 64 + lane] = (bf16_t)(oa / den);
}

// ---------------- 256x256 GEMM, BK=64, counted vmcnt (round-10 config) -----
// 8 waves (2M x 4N), per-wave out 128x64 (acc[8][4]). LDS 128 KiB dynamic.
// One barrier per phase; lgkmcnt(0) BEFORE barrier so barrier-crossing
// certifies all waves' phase reads complete (WAR-safe staging, see r10).
// Stage targets: ph1->(T+1).A kh1 | ph2->(T+1).B kh1 | ph3->(T+2).A kh0 |
// ph4->(T+2).B kh0. vmcnt(8) at ph2/ph4 retires the next-needed half-pair.
// Tail: vmcnt(4) at nt-2, vmcnt(0) at nt-1. Swizzle slot^=(row>>1)&3 both
// sides (measured conflict-free). Requires nt >= 2.
// MODE 0: outb = bf16(acc); MODE 2: outb = bf16(silu(gateb)*acc);
// MODE 3: bf16 partial at outb + blockIdx.z * zstride.
template <int MODE>
__global__ __launch_bounds__(512)
void gemm256_kernel(const bf16_t* __restrict__ A, const bf16_t* __restrict__ Bt,
                    int krow, int kchunk, const int* __restrict__ dN,
                    long zstride,
                    bf16_t* __restrict__ outb, long obstride,
                    const bf16_t* __restrict__ gateb, long gstride) {
  const int N = *dN;
  const int brow = blockIdx.y * 256, bcol = blockIdx.x * 256;
  if (brow >= N) return;
  const size_t koff = (size_t)blockIdx.z * kchunk;

  extern __shared__ __align__(16) bf16_t lds[];
  bf16_t* As = lds;             // elems: buf*16384 + kh*8192 + row*32 + slot*8
  bf16_t* Bs = lds + 32768;

  const int t = threadIdx.x;
  const int lane = t & 63, wid = t >> 6;        // 8 waves
  const int wm = wid >> 2, wn = wid & 3;        // 2 x 4
  const int hi = lane >> 4, lo = lane & 15;

  const int swsrc = ((lane & 3) ^ ((lane >> 3) & 3)) << 3;
  const size_t aoffl = (size_t)(brow + (lane >> 2)) * krow + koff + swsrc;
  const size_t boffl = (size_t)(bcol + (lane >> 2)) * krow + koff + swsrc;
  const size_t chk0 = (size_t)(wid * 32) * krow;
  const size_t chk1 = (size_t)(wid * 32 + 16) * krow;
  const int lst0 = wid * 1024;
  const int lst1 = wid * 1024 + 512;

  const int rsl = (hi ^ ((lo >> 1) & 3)) * 8;
  const int abase = (wm * 128 + lo) * 32 + rsl;   // + m*512 (+kh*8192 +buf)
  const int bbase = (wn * 64 + lo) * 32 + rsl;    // + n*512

  f32x4 acc[8][4] = {};
  const int nt = kchunk >> 6;                     // K-tiles of 64

#define STG_A(T, kh) do {                                        \
    const bf16_t* g_ = A + aoffl + (size_t)(T) * 64 + (kh) * 32; \
    bf16_t* l_ = As + (((T) & 1) << 14) + (kh) * 8192;           \
    GLL16(g_ + chk0, l_ + lst0);                                 \
    GLL16(g_ + chk1, l_ + lst1);                                 \
  } while (0)
#define STG_B(T, kh) do {                                        \
    const bf16_t* g_ = Bt + boffl + (size_t)(T) * 64 + (kh) * 32;\
    bf16_t* l_ = Bs + (((T) & 1) << 14) + (kh) * 8192;           \
    GLL16(g_ + chk0, l_ + lst0);                                 \
    GLL16(g_ + chk1, l_ + lst1);                                 \
  } while (0)

  STG_A(0, 0); STG_B(0, 0); STG_A(0, 1); STG_B(0, 1);
  if (nt > 1) {
    STG_A(1, 0); STG_B(1, 0);
    asm volatile("s_waitcnt vmcnt(8)" ::: "memory");
  } else {
    asm volatile("s_waitcnt vmcnt(4)" ::: "memory");
  }
  __builtin_amdgcn_s_barrier();

  for (int T = 0; T < nt; ++T) {
    const int buf = (T & 1) << 14;
    bf16x8 af[8], b0, b1;
    // ---------- phase 1: (kh0, n=0,1); stage (T+1).A kh1 ----------
#pragma unroll
    for (int m = 0; m < 8; ++m)
      af[m] = *(const bf16x8*)(As + buf + abase + m * 512);
    b0 = *(const bf16x8*)(Bs + buf + bbase);
    b1 = *(const bf16x8*)(Bs + buf + bbase + 512);
    if (T + 1 < nt) STG_A(T + 1, 1);
    asm volatile("s_waitcnt lgkmcnt(0)" ::: "memory");
    __builtin_amdgcn_s_barrier();
    __builtin_amdgcn_s_setprio(1);
#pragma unroll
    for (int m = 0; m < 8; ++m) {
      acc[m][0] = MFMA_BF16(af[m], b0, acc[m][0], 0, 0, 0);
      acc[m][1] = MFMA_BF16(af[m], b1, acc[m][1], 0, 0, 0);
    }
    __builtin_amdgcn_s_setprio(0);
    // ---------- phase 2: (kh0, n=2,3); stage (T+1).B kh1; vmcnt ----------
    b0 = *(const bf16x8*)(Bs + buf + bbase + 1024);
    b1 = *(const bf16x8*)(Bs + buf + bbase + 1536);
    if (T + 1 < nt) STG_B(T + 1, 1);
    if (T < nt - 1) asm volatile("s_waitcnt vmcnt(8) lgkmcnt(0)" ::: "memory");
    else            asm volatile("s_waitcnt vmcnt(0) lgkmcnt(0)" ::: "memory");
    __builtin_amdgcn_s_barrier();
    __builtin_amdgcn_s_setprio(1);
#pragma unroll
    for (int m = 0; m < 8; ++m) {
      acc[m][2] = MFMA_BF16(af[m], b0, acc[m][2], 0, 0, 0);
      acc[m][3] = MFMA_BF16(af[m], b1, acc[m][3], 0, 0, 0);
    }
    __builtin_amdgcn_s_setprio(0);
    // ---------- phase 3: (kh1, n=0,1); stage (T+2).A kh0 ----------
#pragma unroll
    for (int m = 0; m < 8; ++m)
      af[m] = *(const bf16x8*)(As + buf + 8192 + abase + m * 512);
    b0 = *(const bf16x8*)(Bs + buf + 8192 + bbase);
    b1 = *(const bf16x8*)(Bs + buf + 8192 + bbase + 512);
    if (T + 2 < nt) STG_A(T + 2, 0);
    asm volatile("s_waitcnt lgkmcnt(0)" ::: "memory");
    __builtin_amdgcn_s_barrier();
    __builtin_amdgcn_s_setprio(1);
#pragma unroll
    for (int m = 0; m < 8; ++m) {
      acc[m][0] = MFMA_BF16(af[m], b0, acc[m][0], 0, 0, 0);
      acc[m][1] = MFMA_BF16(af[m], b1, acc[m][1], 0, 0, 0);
    }
    __builtin_amdgcn_s_setprio(0);
    // ---------- phase 4: (kh1, n=2,3); stage (T+2).B kh0; vmcnt ----------
    b0 = *(const bf16x8*)(Bs + buf + 8192 + bbase + 1024);
    b1 = *(const bf16x8*)(Bs + buf + 8192 + bbase + 1536);
    if (T + 2 < nt) STG_B(T + 2, 0);
    if (T < nt - 2)       asm volatile("s_waitcnt vmcnt(8) lgkmcnt(0)" ::: "memory");
    else if (T == nt - 2) asm volatile("s_waitcnt vmcnt(4) lgkmcnt(0)" ::: "memory");
    else                  asm volatile("s_waitcnt vmcnt(0) lgkmcnt(0)" ::: "memory");
    __builtin_amdgcn_s_barrier();
    __builtin_amdgcn_s_setprio(1);
#pragma unroll
    for (int m = 0; m < 8; ++m) {
      acc[m][2] = MFMA_BF16(af[m], b0, acc[m][2], 0, 0, 0);
      acc[m][3] = MFMA_BF16(af[m], b1, acc[m][3], 0, 0, 0);
    }
    __builtin_amdgcn_s_setprio(0);
  }
#undef STG_A
#undef STG_B

  const int rbase = brow + wm * 128 + hi * 4;
  const int cbase = bcol + wn * 64 + lo;
  bf16_t* pb = (MODE == 3) ? outb + (size_t)blockIdx.z * zstride : outb;
#pragma unroll
  for (int m = 0; m < 8; ++m) {
#pragma unroll
    for (int n = 0; n < 4; ++n) {
      const int col = cbase + n * 16;
#pragma unroll
      for (int j = 0; j < 4; ++j) {
        const int row = rbase + m * 16 + j;
        if (row < N) {
          float v = acc[m][n][j];
          if (MODE == 2) {
            float g = (float)gateb[(size_t)row * gstride + col];
            float sg = g / (1.0f + expf(-g));
            pb[(size_t)row * obstride + col] = (bf16_t)(sg * v);
          } else {
            pb[(size_t)row * obstride + col] = (bf16_t)v;
          }
        }
      }
    }
  }
}

// ---------------- split-K reduce + residual + optional fused RMSNorm -------
// out[r] (stride ostride) = res[r] (stride rstride) + sum_{z<NZ} part[z][r]
// if x != nullptr: x[r] = bf16(rmsnorm(out[r]) * lnw)   (DMODEL cols)
template <int NZ>
__global__ __launch_bounds__(256)
void reduce_norm_kernel(const bf16_t* __restrict__ part, long zstride,
                        const float* __restrict__ res, long rstride,
                        float* __restrict__ out, long ostride,
                        bf16_t* __restrict__ x, const float* __restrict__ lnw,
                        const int* __restrict__ dN) {
  int r = blockIdx.x; if (r >= *dN) return;
  const int c = threadIdx.x * 8;                // 256*8 == DMODEL exactly
  const float* rv = res + (size_t)r * rstride + c;
  float s[8];
#pragma unroll
  for (int j = 0; j < 8; ++j) s[j] = rv[j];
#pragma unroll
  for (int z = 0; z < NZ; ++z) {
    const bf16x8 v = *(const bf16x8*)(part + (size_t)z * zstride + (size_t)r * DMODEL + c);
#pragma unroll
    for (int j = 0; j < 8; ++j) s[j] += (float)v[j];
  }
  float* o = out + (size_t)r * ostride + c;
#pragma unroll
  for (int j = 0; j < 8; ++j) o[j] = s[j];
  if (x) {
    float ss = 0.f;
#pragma unroll
    for (int j = 0; j < 8; ++j) ss += s[j] * s[j];
    ss = wave_sum(ss);
    __shared__ float ps[4];
    if ((threadIdx.x & 63) == 0) ps[threadIdx.x >> 6] = ss;
    __syncthreads();
    float inv = rsqrtf((ps[0] + ps[1] + ps[2] + ps[3]) * (1.0f / DMODEL) + 1e-6f);
    union { bf16_t b[8]; uint4 q; } u;
#pragma unroll
    for (int j = 0; j < 8; ++j) u.b[j] = (bf16_t)(s[j] * inv * lnw[c + j]);
    *(uint4*)(x + (size_t)r * DMODEL + c) = u.q;
  }
}

// ---------------------------------------------------------------------------
extern "C" void kernel_launch(void* const* d_in, const int* in_sizes, int n_in,
                              void* d_out, int out_size, void* d_ws, size_t ws_size,
                              hipStream_t stream) {
  const float* hs  = (const float*)d_in[0];
  const int*   seq = (const int*)d_in[1];
  const int*   ins = (const int*)d_in[2];
  const float* w_q = (const float*)d_in[3];
  const float* w_k = (const float*)d_in[4];
  const float* w_v = (const float*)d_in[5];
  const float* w_o = (const float*)d_in[6];
  const float* ln1 = (const float*)d_in[7];
  const float* ln2 = (const float*)d_in[8];
  const float* w_g = (const float*)d_in[9];
  const float* w_u = (const float*)d_in[10];
  const float* w_d = (const float*)d_in[11];
  const int  B     = in_sizes[1];
  const long total = (long)in_sizes[0] / DMODEL;

  const size_t WQKV_E = (size_t)QKVDIM * DMODEL;
  const size_t WO_E   = (size_t)DMODEL * DMODEL;
  const size_t WG_E   = (size_t)DFF * DMODEL;

  struct WS {
    int* dN; int* idx;
    bf16_t *Wqkv, *Wo, *Wg, *Wu, *Wd;
    bf16_t* kc; bf16_t* vc; float* hattn; bf16_t* gate;
    bf16_t* part;          // overlay region R: nm*16384 B (down partials)
    bf16_t* o;             // = R          (nm*4096 B; dead during down-GEMM)
    float*  h0;            // = R + nm*4096 (nm*8192 B; dead after p=0's Wo)
    bf16_t* x;             // after R, never aliased
    size_t bytes;
  };
  char* base = (char*)d_ws;
  auto mk = [&](long nm) {
    WS w; size_t o = 0;
    auto alloc = [&](size_t b) { char* p = base + o; o = (o + b + 255) & ~(size_t)255; return p; };
    w.dN    = (int*)alloc(4);
    w.idx   = (int*)alloc((size_t)nm * 4);
    w.Wqkv  = (bf16_t*)alloc(WQKV_E * 2);
    w.Wo    = (bf16_t*)alloc(WO_E * 2);
    w.Wg    = (bf16_t*)alloc(WG_E * 2);
    w.Wu    = (bf16_t*)alloc(WG_E * 2);
    w.Wd    = (bf16_t*)alloc(WG_E * 2);
    w.kc    = (bf16_t*)alloc((size_t)nm * NSTEPS * KVDIM * 2);
    w.vc    = (bf16_t*)alloc((size_t)nm * NSTEPS * KVDIM * 2);
    w.hattn = (float*)alloc((size_t)nm * DMODEL * 4);
    w.gate  = (bf16_t*)alloc((size_t)nm * DFF * 2);
    // overlay region R = down split-K partials (4 * nm * DMODEL bf16).
    // o and h0 live inside R; both are dead when the down-GEMM runs
    // (o consumed by Wo-GEMM; h0 last read at p=0's Wo-reduce).
    char* R = alloc((size_t)nm * DMODEL * 2 * 4);   // nm*16384 B
    w.part  = (bf16_t*)R;
    w.o     = (bf16_t*)R;                            // nm*4096 B
    w.h0    = (float*)(R + (size_t)nm * DMODEL * 2); // nm*8192 B
    w.x     = (bf16_t*)alloc((size_t)nm * DMODEL * 2);
    w.bytes = o;
    return w;
  };
  long nm = ((total + 255) / 256) * 256;
  WS w = mk(nm);
  while (w.bytes > ws_size && nm > 256) { nm -= 256; w = mk(nm); }

  build_idx_kernel<<<1, 512, 0, stream>>>(seq, ins, B, w.idx, w.dN, (int)nm);
  gather_kernel<<<(uint32_t)nm, 256, 0, stream>>>(hs, w.idx, w.h0, w.dN);

  dim3 tb(256);
  wtrans_kernel<<<dim3(DMODEL/32, DMODEL/32), tb, 0, stream>>>(w_q, w.Wqkv, DMODEL, DMODEL);
  wtrans_kernel<<<dim3(KVDIM/32,  DMODEL/32), tb, 0, stream>>>(w_k, w.Wqkv + (size_t)QDIM * DMODEL, DMODEL, KVDIM);
  wtrans_kernel<<<dim3(KVDIM/32,  DMODEL/32), tb, 0, stream>>>(w_v, w.Wqkv + (size_t)(QDIM + KVDIM) * DMODEL, DMODEL, KVDIM);
  wtrans_kernel<<<dim3(DMODEL/32, DMODEL/32), tb, 0, stream>>>(w_o, w.Wo, DMODEL, DMODEL);
  wtrans_kernel<<<dim3(DFF/32,    DMODEL/32), tb, 0, stream>>>(w_g, w.Wg, DMODEL, DFF);
  wtrans_kernel<<<dim3(DFF/32,    DMODEL/32), tb, 0, stream>>>(w_u, w.Wu, DMODEL, DFF);
  wtrans_kernel<<<dim3(DMODEL/32, DFF/32),    tb, 0, stream>>>(w_d, w.Wd, DFF, DMODEL);

  const int gy2 = (int)(nm / 256);
  const uint32_t LDSB = 131072;        // 128 KiB dynamic LDS for gemm256
  float* outF = (float*)d_out;
  const long zsD = (long)nm * DMODEL;   // partial z-stride, DMODEL cols
  const long zsQ = (long)nm * QKVDIM;   // partial z-stride, QKVDIM cols

  for (int p = 0; p < NSTEPS; ++p) {
    const float* hprev = (p == 0) ? w.h0 : outF + (size_t)(p - 1) * DMODEL;
    const long   hstr  = (p == 0) ? DMODEL : (long)NSTEPS * DMODEL;

    // ln1 for p>0 is fused into the previous step's reduce_norm (down).
    if (p == 0)
      rmsnorm_kernel<<<(uint32_t)nm, 256, 0, stream>>>(hprev, hstr, ln1, w.x, w.dN);

    // QKV: split-K=2 (192 blocks, nt=16); bf16 partials in w.gate (dead
    // between down-reduce and gate-GEMM). No reduce: attn consumes directly.
    gemm256_kernel<3><<<dim3(QKVDIM/256, gy2, 2), 512, LDSB, stream>>>(
        w.x, w.Wqkv, DMODEL, DMODEL/2, w.dN, zsQ, w.gate, QKVDIM, nullptr, 0);

    // fused reduce + RoPE + cache-append + attention
    attn_fused_kernel<<<dim3((uint32_t)nm, 8), 256, 0, stream>>>(
        w.gate, zsQ, w.kc, w.vc, w.o, p, w.dN);

    // Wo: split-K=4 (256 blocks, nt=8); partials in w.gate; fused reduce
    // adds residual hprev AND applies ln2 -> x.
    gemm256_kernel<3><<<dim3(DMODEL/256, gy2, 4), 512, LDSB, stream>>>(
        w.o, w.Wo, DMODEL, DMODEL/4, w.dN, zsD, w.gate, DMODEL, nullptr, 0);
    reduce_norm_kernel<4><<<(uint32_t)nm, 256, 0, stream>>>(
        w.gate, zsD, hprev, hstr, w.hattn, DMODEL, w.x, ln2, w.dN);

    // gate / up (full-K gemm256, 256 blocks each)
    gemm256_kernel<0><<<dim3(DFF/256, gy2, 1), 512, LDSB, stream>>>(
        w.x, w.Wg, DMODEL, DMODEL, w.dN, 0, w.gate, DFF, nullptr, 0);
    gemm256_kernel<2><<<dim3(DFF/256, gy2, 1), 512, LDSB, stream>>>(
        w.x, w.Wu, DMODEL, DMODEL, w.dN, 0, w.gate, DFF, w.gate, DFF);

    // down: split-K=4 -> partials overlay {o, h0} (dead here); fused
    // reduce adds hattn residual, writes outF[p], and (p<last) ln1->x.
    gemm256_kernel<3><<<dim3(DMODEL/256, gy2, 4), 512, LDSB, stream>>>(
        w.gate, w.Wd, DFF, DFF/4, w.dN, zsD, w.part, DMODEL, nullptr, 0);
    reduce_norm_kernel<4><<<(uint32_t)nm, 256, 0, stream>>>(
        w.part, zsD, w.hattn, DMODEL, outF + (size_t)p * DMODEL, (long)NSTEPS * DMODEL,
        (p + 1 < NSTEPS) ? w.x : nullptr, ln1, w.dN);
  }
}

// Round 15
// 1684.584 us; speedup vs baseline: 1.3309x; 1.0910x over previous
//
#include <hip/hip_runtime.h>
#include <hip/hip_bf16.h>
#include <stdint.h>

#define DMODEL 2048
#define QDIM   2048
#define KVDIM  512
#define QKVDIM 3072
#define DFF    8192
#define NSTEPS 5

typedef __bf16 bf16_t;
typedef __attribute__((ext_vector_type(8))) __bf16 bf16x8;
typedef __attribute__((ext_vector_type(4))) float f32x4;

// global -> LDS direct DMA, 16B per lane. LDS dest is wave-uniform base;
// HW writes lane i at base + i*16. Requires linear (unpadded) LDS layout.
#define GLL16(g, l)                                                         \
  __builtin_amdgcn_global_load_lds(                                          \
      (const __attribute__((address_space(1))) void*)(g),                    \
      (__attribute__((address_space(3))) void*)(l), 16, 0, 0)

#define MFMA_BF16 __builtin_amdgcn_mfma_f32_16x16x32_bf16

__device__ __forceinline__ float wave_sum(float v) {
#pragma unroll
  for (int o = 32; o > 0; o >>= 1) v += __shfl_xor(v, o, 64);
  return v;
}

// ---------------- index building (handles int32 or int64 length arrays) ----
__global__ void build_idx_kernel(const int* __restrict__ seq, const int* __restrict__ inst,
                                 int B, int* __restrict__ idx, int* __restrict__ dN, int nmax) {
  __shared__ int sbase[64], soff[64], scnt[64], snb;
  if (threadIdx.x == 0) {
    bool is64 = (B >= 2);
    for (int i = 0; i < B && is64; ++i) {
      if (i & 1) { if (seq[i] != 0 || inst[i] != 0) is64 = false; }
      else       { if (seq[i] == 0) is64 = false; }
    }
    int off = 0, row = 0, nb = (B < 64 ? B : 64);
    for (int b = 0; b < nb; ++b) {
      int s = is64 ? seq[2 * b] : seq[b];
      int i = is64 ? inst[2 * b] : inst[b];
      sbase[b] = row; soff[b] = off + i - 1; scnt[b] = s - i;
      row += s - i; off += s;
    }
    snb = nb;
    *dN = row < nmax ? row : nmax;
  }
  __syncthreads();
  int nb = snb;
  for (int b = 0; b < nb; ++b) {
    int cnt = scnt[b], base = sbase[b], o0 = soff[b];
    for (int t = threadIdx.x; t < cnt; t += blockDim.x) {
      int r = base + t;
      if (r < nmax) idx[r] = o0 + t;
    }
  }
}

// ---------------- gather rows into h0 (fp32) -------------------------------
__global__ __launch_bounds__(256)
void gather_kernel(const float* __restrict__ hs, const int* __restrict__ idx,
                   float* __restrict__ h0, const int* __restrict__ dN) {
  int r = blockIdx.x; if (r >= *dN) return;
  const float4* in = (const float4*)(hs + (size_t)idx[r] * DMODEL);
  float4* out = (float4*)(h0 + (size_t)r * DMODEL);
  out[threadIdx.x]       = in[threadIdx.x];
  out[threadIdx.x + 256] = in[threadIdx.x + 256];
}

// ---------------- fp32 -> bf16 transpose of a weight matrix ----------------
// W is [K][Nc] row-major fp32, Wt is [Nc][K] row-major bf16
__global__ __launch_bounds__(256)
void wtrans_kernel(const float* __restrict__ W, bf16_t* __restrict__ Wt, int K, int Nc) {
  __shared__ float tile[32][33];
  int c0 = blockIdx.x * 32, k0 = blockIdx.y * 32;
  int tx = threadIdx.x & 31, ty = threadIdx.x >> 5;
#pragma unroll
  for (int yy = 0; yy < 4; ++yy)
    tile[ty + 8 * yy][tx] = W[(size_t)(k0 + ty + 8 * yy) * Nc + c0 + tx];
  __syncthreads();
#pragma unroll
  for (int yy = 0; yy < 4; ++yy)
    Wt[(size_t)(c0 + ty + 8 * yy) * K + k0 + tx] = (bf16_t)tile[tx][ty + 8 * yy];
}

// ---------------- RMSNorm: fp32 row -> bf16 row (only used at p=0) ---------
__global__ __launch_bounds__(256)
void rmsnorm_kernel(const float* __restrict__ h, long hstride, const float* __restrict__ w,
                    bf16_t* __restrict__ x, const int* __restrict__ dN) {
  int r = blockIdx.x; if (r >= *dN) return;
  const float* row = h + (size_t)r * hstride;
  int t = threadIdx.x;
  float4 v0 = ((const float4*)row)[2 * t];
  float4 v1 = ((const float4*)row)[2 * t + 1];
  float ss = v0.x*v0.x + v0.y*v0.y + v0.z*v0.z + v0.w*v0.w
           + v1.x*v1.x + v1.y*v1.y + v1.z*v1.z + v1.w*v1.w;
  ss = wave_sum(ss);
  __shared__ float part[4];
  if ((t & 63) == 0) part[t >> 6] = ss;
  __syncthreads();
  float inv = rsqrtf((part[0] + part[1] + part[2] + part[3]) * (1.0f / DMODEL) + 1e-6f);
  const float4* wv = (const float4*)w;
  float4 w0 = wv[2 * t], w1 = wv[2 * t + 1];
  union { bf16_t b[8]; uint4 q; } u;
  u.b[0] = (bf16_t)(v0.x * inv * w0.x);
  u.b[1] = (bf16_t)(v0.y * inv * w0.y);
  u.b[2] = (bf16_t)(v0.z * inv * w0.z);
  u.b[3] = (bf16_t)(v0.w * inv * w0.w);
  u.b[4] = (bf16_t)(v1.x * inv * w1.x);
  u.b[5] = (bf16_t)(v1.y * inv * w1.y);
  u.b[6] = (bf16_t)(v1.z * inv * w1.z);
  u.b[7] = (bf16_t)(v1.w * inv * w1.w);
  *(uint4*)(x + (size_t)r * DMODEL + t * 8) = u.q;
}

// ---------------- fused attention at position p ----------------------------
// Reads the QKV split-K=2 bf16 partials directly (fp32 sum in-register),
// applies RoPE(p) to q and to k(p), writes k(p)/v(p) to the cache (wave 0 —
// block (r, kh) is the unique owner), and computes attention with j == p
// served from registers. Replaces reduce_qkv + rope_cache + attn.
__global__ __launch_bounds__(256)
void attn_fused_kernel(const bf16_t* __restrict__ part, long zstride,
                       bf16_t* __restrict__ kc, bf16_t* __restrict__ vc,
                       bf16_t* __restrict__ o, int p, const int* __restrict__ dN) {
  int r = blockIdx.x; if (r >= *dN) return;
  int wid = threadIdx.x >> 6, lane = threadIdx.x & 63;
  int kh = blockIdx.y;                 // kv head 0..7
  int head = kh * 4 + wid;             // q head (4 q-heads share this kv head)
  size_t qb = (size_t)r * QKVDIM;

  int fi = lane & 31;
  float ang = (float)p * expf((float)fi * -0.28782313662425576f); // -ln(1e4)/32
  float cv, sv; sincosf(ang, &sv, &cv);

  // q = partial0 + partial1, then RoPE
  size_t qo = qb + (size_t)head * 64 + lane;
  float q = (float)part[qo] + (float)part[zstride + qo];
  float qp = __shfl_xor(q, 32, 64);
  float qr = q * cv + ((lane < 32) ? -qp : qp) * sv;

  // k(p), v(p) from partials; RoPE k
  size_t kb = qb + QDIM + (size_t)kh * 64 + lane;
  float kraw = (float)part[kb] + (float)part[zstride + kb];
  float kp_ = __shfl_xor(kraw, 32, 64);
  float kr = kraw * cv + ((lane < 32) ? -kp_ : kp_) * sv;
  size_t vb = kb + KVDIM;
  float vnew = (float)part[vb] + (float)part[zstride + vb];

  size_t cbase = (size_t)r * NSTEPS * KVDIM + (size_t)kh * 64 + lane;
  if (wid == 0) {
    kc[cbase + (size_t)p * KVDIM] = (bf16_t)kr;
    vc[cbase + (size_t)p * KVDIM] = (bf16_t)vnew;
  }

  float s[NSTEPS];
#pragma unroll
  for (int j = 0; j < NSTEPS; ++j) {
    s[j] = -1e30f;
    if (j < p) {
      float kj = (float)kc[cbase + (size_t)j * KVDIM];
      s[j] = wave_sum(qr * kj) * 0.125f;
    } else if (j == p) {
      s[j] = wave_sum(qr * (float)(bf16_t)kr) * 0.125f;  // match cached bf16
    }
  }
  float m = s[0];
#pragma unroll
  for (int j = 1; j < NSTEPS; ++j) m = fmaxf(m, s[j]);
  float aw[NSTEPS]; float den = 0.f;
#pragma unroll
  for (int j = 0; j < NSTEPS; ++j) { aw[j] = (j <= p) ? expf(s[j] - m) : 0.f; den += aw[j]; }
  float oa = 0.f;
#pragma unroll
  for (int j = 0; j < NSTEPS; ++j) {
    if (j < p)       oa += aw[j] * (float)vc[cbase + (size_t)j * KVDIM];
    else if (j == p) oa += aw[j] * (float)(bf16_t)vnew;
  }
  o[(size_t)r * QDIM + (size_t)head * 64 + lane] = (bf16_t)(oa / den);
}

// ---------------- 256x256 GEMM, BK=64, counted vmcnt (round-10 config) -----
// 8 waves (2M x 4N), per-wave out 128x64 (acc[8][4]). LDS 128 KiB dynamic.
// One barrier per phase; lgkmcnt(0) BEFORE barrier (WAR-safe, see r10).
// vmcnt(8) at ph2/ph4 retires the next-needed half-pair. Tail vmcnt(4)/(0).
// Swizzle slot^=(row>>1)&3 both sides (measured conflict-free). nt >= 2.
// MODE 0: outb = bf16(acc); MODE 3: bf16 partial at outb + z*zstride.
template <int MODE>
__global__ __launch_bounds__(512)
void gemm256_kernel(const bf16_t* __restrict__ A, const bf16_t* __restrict__ Bt,
                    int krow, int kchunk, const int* __restrict__ dN,
                    long zstride,
                    bf16_t* __restrict__ outb, long obstride) {
  const int N = *dN;
  const int brow = blockIdx.y * 256, bcol = blockIdx.x * 256;
  if (brow >= N) return;
  const size_t koff = (size_t)blockIdx.z * kchunk;

  extern __shared__ __align__(16) bf16_t lds[];
  bf16_t* As = lds;             // elems: buf*16384 + kh*8192 + row*32 + slot*8
  bf16_t* Bs = lds + 32768;

  const int t = threadIdx.x;
  const int lane = t & 63, wid = t >> 6;        // 8 waves
  const int wm = wid >> 2, wn = wid & 3;        // 2 x 4
  const int hi = lane >> 4, lo = lane & 15;

  const int swsrc = ((lane & 3) ^ ((lane >> 3) & 3)) << 3;
  const size_t aoffl = (size_t)(brow + (lane >> 2)) * krow + koff + swsrc;
  const size_t boffl = (size_t)(bcol + (lane >> 2)) * krow + koff + swsrc;
  const size_t chk0 = (size_t)(wid * 32) * krow;
  const size_t chk1 = (size_t)(wid * 32 + 16) * krow;
  const int lst0 = wid * 1024;
  const int lst1 = wid * 1024 + 512;

  const int rsl = (hi ^ ((lo >> 1) & 3)) * 8;
  const int abase = (wm * 128 + lo) * 32 + rsl;   // + m*512 (+kh*8192 +buf)
  const int bbase = (wn * 64 + lo) * 32 + rsl;    // + n*512

  f32x4 acc[8][4] = {};
  const int nt = kchunk >> 6;                     // K-tiles of 64

#define STG_A(T, kh) do {                                        \
    const bf16_t* g_ = A + aoffl + (size_t)(T) * 64 + (kh) * 32; \
    bf16_t* l_ = As + (((T) & 1) << 14) + (kh) * 8192;           \
    GLL16(g_ + chk0, l_ + lst0);                                 \
    GLL16(g_ + chk1, l_ + lst1);                                 \
  } while (0)
#define STG_B(T, kh) do {                                        \
    const bf16_t* g_ = Bt + boffl + (size_t)(T) * 64 + (kh) * 32;\
    bf16_t* l_ = Bs + (((T) & 1) << 14) + (kh) * 8192;           \
    GLL16(g_ + chk0, l_ + lst0);                                 \
    GLL16(g_ + chk1, l_ + lst1);                                 \
  } while (0)

  STG_A(0, 0); STG_B(0, 0); STG_A(0, 1); STG_B(0, 1);
  if (nt > 1) {
    STG_A(1, 0); STG_B(1, 0);
    asm volatile("s_waitcnt vmcnt(8)" ::: "memory");
  } else {
    asm volatile("s_waitcnt vmcnt(4)" ::: "memory");
  }
  __builtin_amdgcn_s_barrier();

  for (int T = 0; T < nt; ++T) {
    const int buf = (T & 1) << 14;
    bf16x8 af[8], b0, b1;
    // ---------- phase 1: (kh0, n=0,1); stage (T+1).A kh1 ----------
#pragma unroll
    for (int m = 0; m < 8; ++m)
      af[m] = *(const bf16x8*)(As + buf + abase + m * 512);
    b0 = *(const bf16x8*)(Bs + buf + bbase);
    b1 = *(const bf16x8*)(Bs + buf + bbase + 512);
    if (T + 1 < nt) STG_A(T + 1, 1);
    asm volatile("s_waitcnt lgkmcnt(0)" ::: "memory");
    __builtin_amdgcn_s_barrier();
    __builtin_amdgcn_s_setprio(1);
#pragma unroll
    for (int m = 0; m < 8; ++m) {
      acc[m][0] = MFMA_BF16(af[m], b0, acc[m][0], 0, 0, 0);
      acc[m][1] = MFMA_BF16(af[m], b1, acc[m][1], 0, 0, 0);
    }
    __builtin_amdgcn_s_setprio(0);
    // ---------- phase 2: (kh0, n=2,3); stage (T+1).B kh1; vmcnt ----------
    b0 = *(const bf16x8*)(Bs + buf + bbase + 1024);
    b1 = *(const bf16x8*)(Bs + buf + bbase + 1536);
    if (T + 1 < nt) STG_B(T + 1, 1);
    if (T < nt - 1) asm volatile("s_waitcnt vmcnt(8) lgkmcnt(0)" ::: "memory");
    else            asm volatile("s_waitcnt vmcnt(0) lgkmcnt(0)" ::: "memory");
    __builtin_amdgcn_s_barrier();
    __builtin_amdgcn_s_setprio(1);
#pragma unroll
    for (int m = 0; m < 8; ++m) {
      acc[m][2] = MFMA_BF16(af[m], b0, acc[m][2], 0, 0, 0);
      acc[m][3] = MFMA_BF16(af[m], b1, acc[m][3], 0, 0, 0);
    }
    __builtin_amdgcn_s_setprio(0);
    // ---------- phase 3: (kh1, n=0,1); stage (T+2).A kh0 ----------
#pragma unroll
    for (int m = 0; m < 8; ++m)
      af[m] = *(const bf16x8*)(As + buf + 8192 + abase + m * 512);
    b0 = *(const bf16x8*)(Bs + buf + 8192 + bbase);
    b1 = *(const bf16x8*)(Bs + buf + 8192 + bbase + 512);
    if (T + 2 < nt) STG_A(T + 2, 0);
    asm volatile("s_waitcnt lgkmcnt(0)" ::: "memory");
    __builtin_amdgcn_s_barrier();
    __builtin_amdgcn_s_setprio(1);
#pragma unroll
    for (int m = 0; m < 8; ++m) {
      acc[m][0] = MFMA_BF16(af[m], b0, acc[m][0], 0, 0, 0);
      acc[m][1] = MFMA_BF16(af[m], b1, acc[m][1], 0, 0, 0);
    }
    __builtin_amdgcn_s_setprio(0);
    // ---------- phase 4: (kh1, n=2,3); stage (T+2).B kh0; vmcnt ----------
    b0 = *(const bf16x8*)(Bs + buf + 8192 + bbase + 1024);
    b1 = *(const bf16x8*)(Bs + buf + 8192 + bbase + 1536);
    if (T + 2 < nt) STG_B(T + 2, 0);
    if (T < nt - 2)       asm volatile("s_waitcnt vmcnt(8) lgkmcnt(0)" ::: "memory");
    else if (T == nt - 2) asm volatile("s_waitcnt vmcnt(4) lgkmcnt(0)" ::: "memory");
    else                  asm volatile("s_waitcnt vmcnt(0) lgkmcnt(0)" ::: "memory");
    __builtin_amdgcn_s_barrier();
    __builtin_amdgcn_s_setprio(1);
#pragma unroll
    for (int m = 0; m < 8; ++m) {
      acc[m][2] = MFMA_BF16(af[m], b0, acc[m][2], 0, 0, 0);
      acc[m][3] = MFMA_BF16(af[m], b1, acc[m][3], 0, 0, 0);
    }
    __builtin_amdgcn_s_setprio(0);
  }
#undef STG_A
#undef STG_B

  const int rbase = brow + wm * 128 + hi * 4;
  const int cbase = bcol + wn * 64 + lo;
  bf16_t* pb = (MODE == 3) ? outb + (size_t)blockIdx.z * zstride : outb;
#pragma unroll
  for (int m = 0; m < 8; ++m) {
#pragma unroll
    for (int n = 0; n < 4; ++n) {
      const int col = cbase + n * 16;
#pragma unroll
      for (int j = 0; j < 4; ++j) {
        const int row = rbase + m * 16 + j;
        if (row < N)
          pb[(size_t)row * obstride + col] = (bf16_t)acc[m][n][j];
      }
    }
  }
}

// ---------------- fused gate+up GEMM: out = silu(x@Wg) * (x@Wu) ------------
// BM=256, BN=128 (DFF cols), BK=64. 8 waves (2M x 4N), per-wave 128x32 per
// matrix: acc_g[8][2] + acc_u[8][2] (128 regs, same budget as gemm256).
// LDS 128 KiB: A[2][2][256x32] + Bg[2][2][128x32] + Bu[2][2][128x32].
// Sync skeleton identical to gemm256 (every stage op = 2 GLLs; positional
// vmcnt retire arithmetic maps 1:1 — Bg+Bu pair replaces the B row-pair).
// Phases: (kh0,gate) | (kh0,up) | (kh1,gate) | (kh1,up); af shared per kh.
// silu applied to fp32 accumulators in the epilogue (no gate round-trip).
__global__ __launch_bounds__(512)
void gemm256gu_kernel(const bf16_t* __restrict__ A, const bf16_t* __restrict__ Wg,
                      const bf16_t* __restrict__ Wu, int krow,
                      const int* __restrict__ dN,
                      bf16_t* __restrict__ outb, long obstride) {
  const int N = *dN;
  const int brow = blockIdx.y * 256, bcol = blockIdx.x * 128;
  if (brow >= N) return;

  extern __shared__ __align__(16) bf16_t lds[];
  bf16_t* As = lds;             // buf*16384 + kh*8192 + row*32 + slot*8
  bf16_t* Bg = lds + 32768;     // buf*8192  + kh*4096 + row*32 + slot*8
  bf16_t* Bu = lds + 49152;

  const int t = threadIdx.x;
  const int lane = t & 63, wid = t >> 6;        // 8 waves
  const int wm = wid >> 2, wn = wid & 3;        // 2 x 4 (cols: 4 x 32)
  const int hi = lane >> 4, lo = lane & 15;

  const int swsrc = ((lane & 3) ^ ((lane >> 3) & 3)) << 3;
  const size_t aoffl = (size_t)(brow + (lane >> 2)) * krow + swsrc;
  const size_t boffl = (size_t)(bcol + (lane >> 2)) * krow + swsrc;
  const size_t chk0 = (size_t)(wid * 32) * krow;        // A rows wid*32+
  const size_t chk1 = (size_t)(wid * 32 + 16) * krow;   // A rows wid*32+16
  const size_t bchk = (size_t)(wid * 16) * krow;        // B rows wid*16+
  const int lst0 = wid * 1024, lst1 = wid * 1024 + 512;
  const int lbst = wid * 512;

  const int rsl = (hi ^ ((lo >> 1) & 3)) * 8;
  const int abase = (wm * 128 + lo) * 32 + rsl;   // + m*512 (+kh*8192 +buf)
  const int bbase = (wn * 32 + lo) * 32 + rsl;    // + n*512 (+kh*4096 +buf)

  f32x4 accg[8][2] = {}, accu[8][2] = {};
  const int nt = krow >> 6;                       // K-tiles of 64 (full K)

#define STG_A(T, kh) do {                                        \
    const bf16_t* g_ = A + aoffl + (size_t)(T) * 64 + (kh) * 32; \
    bf16_t* l_ = As + (((T) & 1) << 14) + (kh) * 8192;           \
    GLL16(g_ + chk0, l_ + lst0);                                 \
    GLL16(g_ + chk1, l_ + lst1);                                 \
  } while (0)
#define STG_GU(T, kh) do {                                       \
    const size_t go_ = boffl + bchk + (size_t)(T) * 64 + (kh) * 32; \
    const int lb_ = (((T) & 1) << 13) + (kh) * 4096 + lbst;      \
    GLL16(Wg + go_, Bg + lb_);                                   \
    GLL16(Wu + go_, Bu + lb_);                                   \
  } while (0)

  STG_A(0, 0); STG_GU(0, 0); STG_A(0, 1); STG_GU(0, 1);
  if (nt > 1) {
    STG_A(1, 0); STG_GU(1, 0);
    asm volatile("s_waitcnt vmcnt(8)" ::: "memory");
  } else {
    asm volatile("s_waitcnt vmcnt(4)" ::: "memory");
  }
  __builtin_amdgcn_s_barrier();

  for (int T = 0; T < nt; ++T) {
    const int abuf = (T & 1) << 14, bbuf = (T & 1) << 13;
    bf16x8 af[8], b0, b1;
    // ---------- phase 1: (kh0, gate); stage (T+1).A kh1 ----------
#pragma unroll
    for (int m = 0; m < 8; ++m)
      af[m] = *(const bf16x8*)(As + abuf + abase + m * 512);
    b0 = *(const bf16x8*)(Bg + bbuf + bbase);
    b1 = *(const bf16x8*)(Bg + bbuf + bbase + 512);
    if (T + 1 < nt) STG_A(T + 1, 1);
    asm volatile("s_waitcnt lgkmcnt(0)" ::: "memory");
    __builtin_amdgcn_s_barrier();
    __builtin_amdgcn_s_setprio(1);
#pragma unroll
    for (int m = 0; m < 8; ++m) {
      accg[m][0] = MFMA_BF16(af[m], b0, accg[m][0], 0, 0, 0);
      accg[m][1] = MFMA_BF16(af[m], b1, accg[m][1], 0, 0, 0);
    }
    __builtin_amdgcn_s_setprio(0);
    // ---------- phase 2: (kh0, up); stage (T+1).GU kh1; vmcnt ----------
    b0 = *(const bf16x8*)(Bu + bbuf + bbase);
    b1 = *(const bf16x8*)(Bu + bbuf + bbase + 512);
    if (T + 1 < nt) STG_GU(T + 1, 1);
    if (T < nt - 1) asm volatile("s_waitcnt vmcnt(8) lgkmcnt(0)" ::: "memory");
    else            asm volatile("s_waitcnt vmcnt(0) lgkmcnt(0)" ::: "memory");
    __builtin_amdgcn_s_barrier();
    __builtin_amdgcn_s_setprio(1);
#pragma unroll
    for (int m = 0; m < 8; ++m) {
      accu[m][0] = MFMA_BF16(af[m], b0, accu[m][0], 0, 0, 0);
      accu[m][1] = MFMA_BF16(af[m], b1, accu[m][1], 0, 0, 0);
    }
    __builtin_amdgcn_s_setprio(0);
    // ---------- phase 3: (kh1, gate); stage (T+2).A kh0 ----------
#pragma unroll
    for (int m = 0; m < 8; ++m)
      af[m] = *(const bf16x8*)(As + abuf + 8192 + abase + m * 512);
    b0 = *(const bf16x8*)(Bg + bbuf + 4096 + bbase);
    b1 = *(const bf16x8*)(Bg + bbuf + 4096 + bbase + 512);
    if (T + 2 < nt) STG_A(T + 2, 0);
    asm volatile("s_waitcnt lgkmcnt(0)" ::: "memory");
    __builtin_amdgcn_s_barrier();
    __builtin_amdgcn_s_setprio(1);
#pragma unroll
    for (int m = 0; m < 8; ++m) {
      accg[m][0] = MFMA_BF16(af[m], b0, accg[m][0], 0, 0, 0);
      accg[m][1] = MFMA_BF16(af[m], b1, accg[m][1], 0, 0, 0);
    }
    __builtin_amdgcn_s_setprio(0);
    // ---------- phase 4: (kh1, up); stage (T+2).GU kh0; vmcnt ----------
    b0 = *(const bf16x8*)(Bu + bbuf + 4096 + bbase);
    b1 = *(const bf16x8*)(Bu + bbuf + 4096 + bbase + 512);
    if (T + 2 < nt) STG_GU(T + 2, 0);
    if (T < nt - 2)       asm volatile("s_waitcnt vmcnt(8) lgkmcnt(0)" ::: "memory");
    else if (T == nt - 2) asm volatile("s_waitcnt vmcnt(4) lgkmcnt(0)" ::: "memory");
    else                  asm volatile("s_waitcnt vmcnt(0) lgkmcnt(0)" ::: "memory");
    __builtin_amdgcn_s_barrier();
    __builtin_amdgcn_s_setprio(1);
#pragma unroll
    for (int m = 0; m < 8; ++m) {
      accu[m][0] = MFMA_BF16(af[m], b0, accu[m][0], 0, 0, 0);
      accu[m][1] = MFMA_BF16(af[m], b1, accu[m][1], 0, 0, 0);
    }
    __builtin_amdgcn_s_setprio(0);
  }
#undef STG_A
#undef STG_GU

  const int rbase = brow + wm * 128 + hi * 4;
  const int cbase = bcol + wn * 32 + lo;
#pragma unroll
  for (int m = 0; m < 8; ++m) {
#pragma unroll
    for (int n = 0; n < 2; ++n) {
      const int col = cbase + n * 16;
#pragma unroll
      for (int j = 0; j < 4; ++j) {
        const int row = rbase + m * 16 + j;
        if (row < N) {
          float g = accg[m][n][j];
          float sg = g / (1.0f + expf(-g));
          outb[(size_t)row * obstride + col] = (bf16_t)(sg * accu[m][n][j]);
        }
      }
    }
  }
}

// ---------------- split-K reduce + residual + optional fused RMSNorm -------
// out[r] (stride ostride) = res[r] (stride rstride) + sum_{z<NZ} part[z][r]
// if x != nullptr: x[r] = bf16(rmsnorm(out[r]) * lnw)   (DMODEL cols)
template <int NZ>
__global__ __launch_bounds__(256)
void reduce_norm_kernel(const bf16_t* __restrict__ part, long zstride,
                        const float* __restrict__ res, long rstride,
                        float* __restrict__ out, long ostride,
                        bf16_t* __restrict__ x, const float* __restrict__ lnw,
                        const int* __restrict__ dN) {
  int r = blockIdx.x; if (r >= *dN) return;
  const int c = threadIdx.x * 8;                // 256*8 == DMODEL exactly
  const float* rv = res + (size_t)r * rstride + c;
  float s[8];
#pragma unroll
  for (int j = 0; j < 8; ++j) s[j] = rv[j];
#pragma unroll
  for (int z = 0; z < NZ; ++z) {
    const bf16x8 v = *(const bf16x8*)(part + (size_t)z * zstride + (size_t)r * DMODEL + c);
#pragma unroll
    for (int j = 0; j < 8; ++j) s[j] += (float)v[j];
  }
  float* o = out + (size_t)r * ostride + c;
#pragma unroll
  for (int j = 0; j < 8; ++j) o[j] = s[j];
  if (x) {
    float ss = 0.f;
#pragma unroll
    for (int j = 0; j < 8; ++j) ss += s[j] * s[j];
    ss = wave_sum(ss);
    __shared__ float ps[4];
    if ((threadIdx.x & 63) == 0) ps[threadIdx.x >> 6] = ss;
    __syncthreads();
    float inv = rsqrtf((ps[0] + ps[1] + ps[2] + ps[3]) * (1.0f / DMODEL) + 1e-6f);
    union { bf16_t b[8]; uint4 q; } u;
#pragma unroll
    for (int j = 0; j < 8; ++j) u.b[j] = (bf16_t)(s[j] * inv * lnw[c + j]);
    *(uint4*)(x + (size_t)r * DMODEL + c) = u.q;
  }
}

// ---------------------------------------------------------------------------
extern "C" void kernel_launch(void* const* d_in, const int* in_sizes, int n_in,
                              void* d_out, int out_size, void* d_ws, size_t ws_size,
                              hipStream_t stream) {
  const float* hs  = (const float*)d_in[0];
  const int*   seq = (const int*)d_in[1];
  const int*   ins = (const int*)d_in[2];
  const float* w_q = (const float*)d_in[3];
  const float* w_k = (const float*)d_in[4];
  const float* w_v = (const float*)d_in[5];
  const float* w_o = (const float*)d_in[6];
  const float* ln1 = (const float*)d_in[7];
  const float* ln2 = (const float*)d_in[8];
  const float* w_g = (const float*)d_in[9];
  const float* w_u = (const float*)d_in[10];
  const float* w_d = (const float*)d_in[11];
  const int  B     = in_sizes[1];
  const long total = (long)in_sizes[0] / DMODEL;

  const size_t WQKV_E = (size_t)QKVDIM * DMODEL;
  const size_t WO_E   = (size_t)DMODEL * DMODEL;
  const size_t WG_E   = (size_t)DFF * DMODEL;

  struct WS {
    int* dN; int* idx;
    bf16_t *Wqkv, *Wo, *Wg, *Wu, *Wd;
    bf16_t* kc; bf16_t* vc; float* hattn; bf16_t* gate;
    bf16_t* part;          // overlay region R: nm*16384 B (down partials)
    bf16_t* o;             // = R          (nm*4096 B; dead during down-GEMM)
    float*  h0;            // = R + nm*4096 (nm*8192 B; dead after p=0's Wo)
    bf16_t* x;             // after R, never aliased
    size_t bytes;
  };
  char* base = (char*)d_ws;
  auto mk = [&](long nm) {
    WS w; size_t o = 0;
    auto alloc = [&](size_t b) { char* p = base + o; o = (o + b + 255) & ~(size_t)255; return p; };
    w.dN    = (int*)alloc(4);
    w.idx   = (int*)alloc((size_t)nm * 4);
    w.Wqkv  = (bf16_t*)alloc(WQKV_E * 2);
    w.Wo    = (bf16_t*)alloc(WO_E * 2);
    w.Wg    = (bf16_t*)alloc(WG_E * 2);
    w.Wu    = (bf16_t*)alloc(WG_E * 2);
    w.Wd    = (bf16_t*)alloc(WG_E * 2);
    w.kc    = (bf16_t*)alloc((size_t)nm * NSTEPS * KVDIM * 2);
    w.vc    = (bf16_t*)alloc((size_t)nm * NSTEPS * KVDIM * 2);
    w.hattn = (float*)alloc((size_t)nm * DMODEL * 4);
    w.gate  = (bf16_t*)alloc((size_t)nm * DFF * 2);
    // overlay region R = down split-K partials (4 * nm * DMODEL bf16).
    // o and h0 live inside R; both are dead when the down-GEMM runs.
    char* R = alloc((size_t)nm * DMODEL * 2 * 4);   // nm*16384 B
    w.part  = (bf16_t*)R;
    w.o     = (bf16_t*)R;                            // nm*4096 B
    w.h0    = (float*)(R + (size_t)nm * DMODEL * 2); // nm*8192 B
    w.x     = (bf16_t*)alloc((size_t)nm * DMODEL * 2);
    w.bytes = o;
    return w;
  };
  long nm = ((total + 255) / 256) * 256;
  WS w = mk(nm);
  while (w.bytes > ws_size && nm > 256) { nm -= 256; w = mk(nm); }

  build_idx_kernel<<<1, 512, 0, stream>>>(seq, ins, B, w.idx, w.dN, (int)nm);
  gather_kernel<<<(uint32_t)nm, 256, 0, stream>>>(hs, w.idx, w.h0, w.dN);

  dim3 tb(256);
  wtrans_kernel<<<dim3(DMODEL/32, DMODEL/32), tb, 0, stream>>>(w_q, w.Wqkv, DMODEL, DMODEL);
  wtrans_kernel<<<dim3(KVDIM/32,  DMODEL/32), tb, 0, stream>>>(w_k, w.Wqkv + (size_t)QDIM * DMODEL, DMODEL, KVDIM);
  wtrans_kernel<<<dim3(KVDIM/32,  DMODEL/32), tb, 0, stream>>>(w_v, w.Wqkv + (size_t)(QDIM + KVDIM) * DMODEL, DMODEL, KVDIM);
  wtrans_kernel<<<dim3(DMODEL/32, DMODEL/32), tb, 0, stream>>>(w_o, w.Wo, DMODEL, DMODEL);
  wtrans_kernel<<<dim3(DFF/32,    DMODEL/32), tb, 0, stream>>>(w_g, w.Wg, DMODEL, DFF);
  wtrans_kernel<<<dim3(DFF/32,    DMODEL/32), tb, 0, stream>>>(w_u, w.Wu, DMODEL, DFF);
  wtrans_kernel<<<dim3(DMODEL/32, DFF/32),    tb, 0, stream>>>(w_d, w.Wd, DFF, DMODEL);

  const int gy2 = (int)(nm / 256);
  const uint32_t LDSB = 131072;        // 128 KiB dynamic LDS
  float* outF = (float*)d_out;
  const long zsD = (long)nm * DMODEL;   // partial z-stride, DMODEL cols
  const long zsQ = (long)nm * QKVDIM;   // partial z-stride, QKVDIM cols

  for (int p = 0; p < NSTEPS; ++p) {
    const float* hprev = (p == 0) ? w.h0 : outF + (size_t)(p - 1) * DMODEL;
    const long   hstr  = (p == 0) ? DMODEL : (long)NSTEPS * DMODEL;

    // ln1 for p>0 is fused into the previous step's reduce_norm (down).
    if (p == 0)
      rmsnorm_kernel<<<(uint32_t)nm, 256, 0, stream>>>(hprev, hstr, ln1, w.x, w.dN);

    // QKV: split-K=2 (192 blocks, nt=16); bf16 partials in w.gate (dead
    // between down-reduce and gate/up-GEMM). attn consumes directly.
    gemm256_kernel<3><<<dim3(QKVDIM/256, gy2, 2), 512, LDSB, stream>>>(
        w.x, w.Wqkv, DMODEL, DMODEL/2, w.dN, zsQ, w.gate, QKVDIM);

    // fused reduce + RoPE + cache-append + attention
    attn_fused_kernel<<<dim3((uint32_t)nm, 8), 256, 0, stream>>>(
        w.gate, zsQ, w.kc, w.vc, w.o, p, w.dN);

    // Wo: split-K=4 (256 blocks, nt=8); partials in w.gate; fused reduce
    // adds residual hprev AND applies ln2 -> x.
    gemm256_kernel<3><<<dim3(DMODEL/256, gy2, 4), 512, LDSB, stream>>>(
        w.o, w.Wo, DMODEL, DMODEL/4, w.dN, zsD, w.gate, DMODEL);
    reduce_norm_kernel<4><<<(uint32_t)nm, 256, 0, stream>>>(
        w.gate, zsD, hprev, hstr, w.hattn, DMODEL, w.x, ln2, w.dN);

    // fused gate+up: out = silu(x@Wg) * (x@Wu), no intermediate round-trip
    gemm256gu_kernel<<<dim3(DFF/128, gy2, 1), 512, LDSB, stream>>>(
        w.x, w.Wg, w.Wu, DMODEL, w.dN, w.gate, DFF);

    // down: split-K=4 -> partials overlay {o, h0} (dead here); fused
    // reduce adds hattn residual, writes outF[p], and (p<last) ln1->x.
    gemm256_kernel<3><<<dim3(DMODEL/256, gy2, 4), 512, LDSB, stream>>>(
        w.gate, w.Wd, DFF, DFF/4, w.dN, zsD, w.part, DMODEL);
    reduce_norm_kernel<4><<<(uint32_t)nm, 256, 0, stream>>>(
        w.part, zsD, w.hattn, DMODEL, outF + (size_t)p * DMODEL, (long)NSTEPS * DMODEL,
        (p + 1 < NSTEPS) ? w.x : nullptr, ln1, w.dN);
  }
}

// Round 16
// 1680.017 us; speedup vs baseline: 1.3345x; 1.0027x over previous
//
#include <hip/hip_runtime.h>
#include <hip/hip_bf16.h>
#include <stdint.h>

#define DMODEL 2048
#define QDIM   2048
#define KVDIM  512
#define QKVDIM 3072
#define DFF    8192
#define NSTEPS 5

typedef __bf16 bf16_t;
typedef __attribute__((ext_vector_type(8))) __bf16 bf16x8;
typedef __attribute__((ext_vector_type(4))) float f32x4;

// global -> LDS direct DMA, 16B per lane. LDS dest is wave-uniform base;
// HW writes lane i at base + i*16. Requires linear (unpadded) LDS layout.
#define GLL16(g, l)                                                         \
  __builtin_amdgcn_global_load_lds(                                          \
      (const __attribute__((address_space(1))) void*)(g),                    \
      (__attribute__((address_space(3))) void*)(l), 16, 0, 0)

#define MFMA_BF16 __builtin_amdgcn_mfma_f32_16x16x32_bf16

__device__ __forceinline__ float wave_sum(float v) {
#pragma unroll
  for (int o = 32; o > 0; o >>= 1) v += __shfl_xor(v, o, 64);
  return v;
}

// ---------------- index building (handles int32 or int64 length arrays) ----
__global__ void build_idx_kernel(const int* __restrict__ seq, const int* __restrict__ inst,
                                 int B, int* __restrict__ idx, int* __restrict__ dN, int nmax) {
  __shared__ int sbase[64], soff[64], scnt[64], snb;
  if (threadIdx.x == 0) {
    bool is64 = (B >= 2);
    for (int i = 0; i < B && is64; ++i) {
      if (i & 1) { if (seq[i] != 0 || inst[i] != 0) is64 = false; }
      else       { if (seq[i] == 0) is64 = false; }
    }
    int off = 0, row = 0, nb = (B < 64 ? B : 64);
    for (int b = 0; b < nb; ++b) {
      int s = is64 ? seq[2 * b] : seq[b];
      int i = is64 ? inst[2 * b] : inst[b];
      sbase[b] = row; soff[b] = off + i - 1; scnt[b] = s - i;
      row += s - i; off += s;
    }
    snb = nb;
    *dN = row < nmax ? row : nmax;
  }
  __syncthreads();
  int nb = snb;
  for (int b = 0; b < nb; ++b) {
    int cnt = scnt[b], base = sbase[b], o0 = soff[b];
    for (int t = threadIdx.x; t < cnt; t += blockDim.x) {
      int r = base + t;
      if (r < nmax) idx[r] = o0 + t;
    }
  }
}

// ---------------- gather rows into h0 (fp32) -------------------------------
__global__ __launch_bounds__(256)
void gather_kernel(const float* __restrict__ hs, const int* __restrict__ idx,
                   float* __restrict__ h0, const int* __restrict__ dN) {
  int r = blockIdx.x; if (r >= *dN) return;
  const float4* in = (const float4*)(hs + (size_t)idx[r] * DMODEL);
  float4* out = (float4*)(h0 + (size_t)r * DMODEL);
  out[threadIdx.x]       = in[threadIdx.x];
  out[threadIdx.x + 256] = in[threadIdx.x + 256];
}

// ---------------- fp32 -> bf16 transpose of a weight matrix ----------------
// W is [K][Nc] row-major fp32, Wt is [Nc][K] row-major bf16
__global__ __launch_bounds__(256)
void wtrans_kernel(const float* __restrict__ W, bf16_t* __restrict__ Wt, int K, int Nc) {
  __shared__ float tile[32][33];
  int c0 = blockIdx.x * 32, k0 = blockIdx.y * 32;
  int tx = threadIdx.x & 31, ty = threadIdx.x >> 5;
#pragma unroll
  for (int yy = 0; yy < 4; ++yy)
    tile[ty + 8 * yy][tx] = W[(size_t)(k0 + ty + 8 * yy) * Nc + c0 + tx];
  __syncthreads();
#pragma unroll
  for (int yy = 0; yy < 4; ++yy)
    Wt[(size_t)(c0 + ty + 8 * yy) * K + k0 + tx] = (bf16_t)tile[tx][ty + 8 * yy];
}

// ---------------- RMSNorm: fp32 row -> bf16 row (only used at p=0) ---------
__global__ __launch_bounds__(256)
void rmsnorm_kernel(const float* __restrict__ h, long hstride, const float* __restrict__ w,
                    bf16_t* __restrict__ x, const int* __restrict__ dN) {
  int r = blockIdx.x; if (r >= *dN) return;
  const float* row = h + (size_t)r * hstride;
  int t = threadIdx.x;
  float4 v0 = ((const float4*)row)[2 * t];
  float4 v1 = ((const float4*)row)[2 * t + 1];
  float ss = v0.x*v0.x + v0.y*v0.y + v0.z*v0.z + v0.w*v0.w
           + v1.x*v1.x + v1.y*v1.y + v1.z*v1.z + v1.w*v1.w;
  ss = wave_sum(ss);
  __shared__ float part[4];
  if ((t & 63) == 0) part[t >> 6] = ss;
  __syncthreads();
  float inv = rsqrtf((part[0] + part[1] + part[2] + part[3]) * (1.0f / DMODEL) + 1e-6f);
  const float4* wv = (const float4*)w;
  float4 w0 = wv[2 * t], w1 = wv[2 * t + 1];
  union { bf16_t b[8]; uint4 q; } u;
  u.b[0] = (bf16_t)(v0.x * inv * w0.x);
  u.b[1] = (bf16_t)(v0.y * inv * w0.y);
  u.b[2] = (bf16_t)(v0.z * inv * w0.z);
  u.b[3] = (bf16_t)(v0.w * inv * w0.w);
  u.b[4] = (bf16_t)(v1.x * inv * w1.x);
  u.b[5] = (bf16_t)(v1.y * inv * w1.y);
  u.b[6] = (bf16_t)(v1.z * inv * w1.z);
  u.b[7] = (bf16_t)(v1.w * inv * w1.w);
  *(uint4*)(x + (size_t)r * DMODEL + t * 8) = u.q;
}

// ---------------- fused attention at position p ----------------------------
// Reads the QKV split-K=2 bf16 partials directly (fp32 sum in-register),
// applies RoPE(p) to q and to k(p), writes k(p)/v(p) to the cache (wave 0 —
// block (r, kh) is the unique owner), and computes attention with j == p
// served from registers.
__global__ __launch_bounds__(256)
void attn_fused_kernel(const bf16_t* __restrict__ part, long zstride,
                       bf16_t* __restrict__ kc, bf16_t* __restrict__ vc,
                       bf16_t* __restrict__ o, int p, const int* __restrict__ dN) {
  int r = blockIdx.x; if (r >= *dN) return;
  int wid = threadIdx.x >> 6, lane = threadIdx.x & 63;
  int kh = blockIdx.y;                 // kv head 0..7
  int head = kh * 4 + wid;             // q head (4 q-heads share this kv head)
  size_t qb = (size_t)r * QKVDIM;

  int fi = lane & 31;
  float ang = (float)p * expf((float)fi * -0.28782313662425576f); // -ln(1e4)/32
  float cv, sv; sincosf(ang, &sv, &cv);

  // q = partial0 + partial1, then RoPE
  size_t qo = qb + (size_t)head * 64 + lane;
  float q = (float)part[qo] + (float)part[zstride + qo];
  float qp = __shfl_xor(q, 32, 64);
  float qr = q * cv + ((lane < 32) ? -qp : qp) * sv;

  // k(p), v(p) from partials; RoPE k
  size_t kb = qb + QDIM + (size_t)kh * 64 + lane;
  float kraw = (float)part[kb] + (float)part[zstride + kb];
  float kp_ = __shfl_xor(kraw, 32, 64);
  float kr = kraw * cv + ((lane < 32) ? -kp_ : kp_) * sv;
  size_t vb = kb + KVDIM;
  float vnew = (float)part[vb] + (float)part[zstride + vb];

  size_t cbase = (size_t)r * NSTEPS * KVDIM + (size_t)kh * 64 + lane;
  if (wid == 0) {
    kc[cbase + (size_t)p * KVDIM] = (bf16_t)kr;
    vc[cbase + (size_t)p * KVDIM] = (bf16_t)vnew;
  }

  float s[NSTEPS];
#pragma unroll
  for (int j = 0; j < NSTEPS; ++j) {
    s[j] = -1e30f;
    if (j < p) {
      float kj = (float)kc[cbase + (size_t)j * KVDIM];
      s[j] = wave_sum(qr * kj) * 0.125f;
    } else if (j == p) {
      s[j] = wave_sum(qr * (float)(bf16_t)kr) * 0.125f;  // match cached bf16
    }
  }
  float m = s[0];
#pragma unroll
  for (int j = 1; j < NSTEPS; ++j) m = fmaxf(m, s[j]);
  float aw[NSTEPS]; float den = 0.f;
#pragma unroll
  for (int j = 0; j < NSTEPS; ++j) { aw[j] = (j <= p) ? expf(s[j] - m) : 0.f; den += aw[j]; }
  float oa = 0.f;
#pragma unroll
  for (int j = 0; j < NSTEPS; ++j) {
    if (j < p)       oa += aw[j] * (float)vc[cbase + (size_t)j * KVDIM];
    else if (j == p) oa += aw[j] * (float)(bf16_t)vnew;
  }
  o[(size_t)r * QDIM + (size_t)head * 64 + lane] = (bf16_t)(oa / den);
}

// ---------------- dual-B 256-row GEMM, BK=64, counted vmcnt ----------------
// Round-16: the round-15 gu skeleton (measured 982 TF / MfmaUtil 42%)
// generalized to all GEMMs. B is consumed as TWO independent 128-row
// streams staged into separate LDS regions; phases alternate (kh, stream).
// MODE 2: B0=Wg, B1=Wu; out = bf16(silu(acc0)*acc1), block cols = 128.
// MODE 0/3: B0 = B1 = Bt; stream1 rows offset +128 -> block cols = 256,
//   out cols [bcol, bcol+128) from acc0 and [bcol+128, bcol+256) from acc1.
//   MODE 3 writes bf16 partial at outb + blockIdx.z * zstride.
// 8 waves (2M x 4N); per-wave 128x32 per stream: acc0[8][2]+acc1[8][2].
// LDS 128 KiB: A[2][2][256x32] + B0[2][2][128x32] + B1[2][2][128x32].
// Sync skeleton identical to rounds 10-15 (every stage op = 2 GLLs;
// positional vmcnt retire arithmetic unchanged). Swizzle slot^=(row>>1)&3
// both sides (measured conflict-free). Requires nt >= 2.
template <int MODE>
__global__ __launch_bounds__(512)
void gemm256d_kernel(const bf16_t* __restrict__ A, const bf16_t* __restrict__ B0,
                     const bf16_t* __restrict__ B1, int krow, int kchunk,
                     const int* __restrict__ dN, long zstride,
                     bf16_t* __restrict__ outb, long obstride) {
  const int N = *dN;
  const int brow = blockIdx.y * 256;
  const int bcol = blockIdx.x * ((MODE == 2) ? 128 : 256);
  if (brow >= N) return;
  const size_t koff = (size_t)blockIdx.z * kchunk;

  extern __shared__ __align__(16) bf16_t lds[];
  bf16_t* As  = lds;            // buf*16384 + kh*8192 + row*32 + slot*8
  bf16_t* B0s = lds + 32768;    // buf*8192  + kh*4096 + row*32 + slot*8
  bf16_t* B1s = lds + 49152;

  const int t = threadIdx.x;
  const int lane = t & 63, wid = t >> 6;        // 8 waves
  const int wm = wid >> 2, wn = wid & 3;        // 2 x 4 (cols: 4 x 32)
  const int hi = lane >> 4, lo = lane & 15;

  const int swsrc = ((lane & 3) ^ ((lane >> 3) & 3)) << 3;
  const size_t aoffl = (size_t)(brow + (lane >> 2)) * krow + koff + swsrc;
  const size_t b0off = (size_t)(bcol + (lane >> 2)) * krow + koff + swsrc;
  const size_t b1off = b0off + ((MODE == 2) ? 0 : (size_t)128 * krow);
  const size_t chk0 = (size_t)(wid * 32) * krow;        // A rows wid*32+
  const size_t chk1 = (size_t)(wid * 32 + 16) * krow;   // A rows wid*32+16
  const size_t bchk = (size_t)(wid * 16) * krow;        // B rows wid*16+
  const int lst0 = wid * 1024, lst1 = wid * 1024 + 512;
  const int lbst = wid * 512;

  const int rsl = (hi ^ ((lo >> 1) & 3)) * 8;
  const int abase = (wm * 128 + lo) * 32 + rsl;   // + m*512 (+kh*8192 +buf)
  const int bbase = (wn * 32 + lo) * 32 + rsl;    // + n*512 (+kh*4096 +buf)

  f32x4 acc0[8][2] = {}, acc1[8][2] = {};
  const int nt = kchunk >> 6;                     // K-tiles of 64

#define STG_A(T, kh) do {                                        \
    const bf16_t* g_ = A + aoffl + (size_t)(T) * 64 + (kh) * 32; \
    bf16_t* l_ = As + (((T) & 1) << 14) + (kh) * 8192;           \
    GLL16(g_ + chk0, l_ + lst0);                                 \
    GLL16(g_ + chk1, l_ + lst1);                                 \
  } while (0)
#define STG_B(T, kh) do {                                        \
    const size_t go_ = bchk + (size_t)(T) * 64 + (kh) * 32;      \
    const int lb_ = (((T) & 1) << 13) + (kh) * 4096 + lbst;      \
    GLL16(B0 + b0off + go_, B0s + lb_);                          \
    GLL16(B1 + b1off + go_, B1s + lb_);                          \
  } while (0)

  STG_A(0, 0); STG_B(0, 0); STG_A(0, 1); STG_B(0, 1);
  if (nt > 1) {
    STG_A(1, 0); STG_B(1, 0);
    asm volatile("s_waitcnt vmcnt(8)" ::: "memory");
  } else {
    asm volatile("s_waitcnt vmcnt(4)" ::: "memory");
  }
  __builtin_amdgcn_s_barrier();

  for (int T = 0; T < nt; ++T) {
    const int abuf = (T & 1) << 14, bbuf = (T & 1) << 13;
    bf16x8 af[8], b0, b1;
    // ---------- phase 1: (kh0, stream0); stage (T+1).A kh1 ----------
#pragma unroll
    for (int m = 0; m < 8; ++m)
      af[m] = *(const bf16x8*)(As + abuf + abase + m * 512);
    b0 = *(const bf16x8*)(B0s + bbuf + bbase);
    b1 = *(const bf16x8*)(B0s + bbuf + bbase + 512);
    if (T + 1 < nt) STG_A(T + 1, 1);
    asm volatile("s_waitcnt lgkmcnt(0)" ::: "memory");
    __builtin_amdgcn_s_barrier();
    __builtin_amdgcn_s_setprio(1);
#pragma unroll
    for (int m = 0; m < 8; ++m) {
      acc0[m][0] = MFMA_BF16(af[m], b0, acc0[m][0], 0, 0, 0);
      acc0[m][1] = MFMA_BF16(af[m], b1, acc0[m][1], 0, 0, 0);
    }
    __builtin_amdgcn_s_setprio(0);
    // ---------- phase 2: (kh0, stream1); stage (T+1).B kh1; vmcnt ----------
    b0 = *(const bf16x8*)(B1s + bbuf + bbase);
    b1 = *(const bf16x8*)(B1s + bbuf + bbase + 512);
    if (T + 1 < nt) STG_B(T + 1, 1);
    if (T < nt - 1) asm volatile("s_waitcnt vmcnt(8) lgkmcnt(0)" ::: "memory");
    else            asm volatile("s_waitcnt vmcnt(0) lgkmcnt(0)" ::: "memory");
    __builtin_amdgcn_s_barrier();
    __builtin_amdgcn_s_setprio(1);
#pragma unroll
    for (int m = 0; m < 8; ++m) {
      acc1[m][0] = MFMA_BF16(af[m], b0, acc1[m][0], 0, 0, 0);
      acc1[m][1] = MFMA_BF16(af[m], b1, acc1[m][1], 0, 0, 0);
    }
    __builtin_amdgcn_s_setprio(0);
    // ---------- phase 3: (kh1, stream0); stage (T+2).A kh0 ----------
#pragma unroll
    for (int m = 0; m < 8; ++m)
      af[m] = *(const bf16x8*)(As + abuf + 8192 + abase + m * 512);
    b0 = *(const bf16x8*)(B0s + bbuf + 4096 + bbase);
    b1 = *(const bf16x8*)(B0s + bbuf + 4096 + bbase + 512);
    if (T + 2 < nt) STG_A(T + 2, 0);
    asm volatile("s_waitcnt lgkmcnt(0)" ::: "memory");
    __builtin_amdgcn_s_barrier();
    __builtin_amdgcn_s_setprio(1);
#pragma unroll
    for (int m = 0; m < 8; ++m) {
      acc0[m][0] = MFMA_BF16(af[m], b0, acc0[m][0], 0, 0, 0);
      acc0[m][1] = MFMA_BF16(af[m], b1, acc0[m][1], 0, 0, 0);
    }
    __builtin_amdgcn_s_setprio(0);
    // ---------- phase 4: (kh1, stream1); stage (T+2).B kh0; vmcnt ----------
    b0 = *(const bf16x8*)(B1s + bbuf + 4096 + bbase);
    b1 = *(const bf16x8*)(B1s + bbuf + 4096 + bbase + 512);
    if (T + 2 < nt) STG_B(T + 2, 0);
    if (T < nt - 2)       asm volatile("s_waitcnt vmcnt(8) lgkmcnt(0)" ::: "memory");
    else if (T == nt - 2) asm volatile("s_waitcnt vmcnt(4) lgkmcnt(0)" ::: "memory");
    else                  asm volatile("s_waitcnt vmcnt(0) lgkmcnt(0)" ::: "memory");
    __builtin_amdgcn_s_barrier();
    __builtin_amdgcn_s_setprio(1);
#pragma unroll
    for (int m = 0; m < 8; ++m) {
      acc1[m][0] = MFMA_BF16(af[m], b0, acc1[m][0], 0, 0, 0);
      acc1[m][1] = MFMA_BF16(af[m], b1, acc1[m][1], 0, 0, 0);
    }
    __builtin_amdgcn_s_setprio(0);
  }
#undef STG_A
#undef STG_B

  const int rbase = brow + wm * 128 + hi * 4;
  const int cb0 = bcol + wn * 32 + lo;
  bf16_t* pb = (MODE == 3) ? outb + (size_t)blockIdx.z * zstride : outb;
#pragma unroll
  for (int m = 0; m < 8; ++m) {
#pragma unroll
    for (int n = 0; n < 2; ++n) {
      const int col = cb0 + n * 16;
#pragma unroll
      for (int j = 0; j < 4; ++j) {
        const int row = rbase + m * 16 + j;
        if (row < N) {
          if (MODE == 2) {
            float g = acc0[m][n][j];
            float sg = g / (1.0f + expf(-g));
            pb[(size_t)row * obstride + col] = (bf16_t)(sg * acc1[m][n][j]);
          } else {
            pb[(size_t)row * obstride + col]       = (bf16_t)acc0[m][n][j];
            pb[(size_t)row * obstride + col + 128] = (bf16_t)acc1[m][n][j];
          }
        }
      }
    }
  }
}

// ---------------- split-K reduce + residual + optional fused RMSNorm -------
// out[r] (stride ostride) = res[r] (stride rstride) + sum_{z<NZ} part[z][r]
// if x != nullptr: x[r] = bf16(rmsnorm(out[r]) * lnw)   (DMODEL cols)
template <int NZ>
__global__ __launch_bounds__(256)
void reduce_norm_kernel(const bf16_t* __restrict__ part, long zstride,
                        const float* __restrict__ res, long rstride,
                        float* __restrict__ out, long ostride,
                        bf16_t* __restrict__ x, const float* __restrict__ lnw,
                        const int* __restrict__ dN) {
  int r = blockIdx.x; if (r >= *dN) return;
  const int c = threadIdx.x * 8;                // 256*8 == DMODEL exactly
  const float* rv = res + (size_t)r * rstride + c;
  float s[8];
#pragma unroll
  for (int j = 0; j < 8; ++j) s[j] = rv[j];
#pragma unroll
  for (int z = 0; z < NZ; ++z) {
    const bf16x8 v = *(const bf16x8*)(part + (size_t)z * zstride + (size_t)r * DMODEL + c);
#pragma unroll
    for (int j = 0; j < 8; ++j) s[j] += (float)v[j];
  }
  float* o = out + (size_t)r * ostride + c;
#pragma unroll
  for (int j = 0; j < 8; ++j) o[j] = s[j];
  if (x) {
    float ss = 0.f;
#pragma unroll
    for (int j = 0; j < 8; ++j) ss += s[j] * s[j];
    ss = wave_sum(ss);
    __shared__ float ps[4];
    if ((threadIdx.x & 63) == 0) ps[threadIdx.x >> 6] = ss;
    __syncthreads();
    float inv = rsqrtf((ps[0] + ps[1] + ps[2] + ps[3]) * (1.0f / DMODEL) + 1e-6f);
    union { bf16_t b[8]; uint4 q; } u;
#pragma unroll
    for (int j = 0; j < 8; ++j) u.b[j] = (bf16_t)(s[j] * inv * lnw[c + j]);
    *(uint4*)(x + (size_t)r * DMODEL + c) = u.q;
  }
}

// ---------------------------------------------------------------------------
extern "C" void kernel_launch(void* const* d_in, const int* in_sizes, int n_in,
                              void* d_out, int out_size, void* d_ws, size_t ws_size,
                              hipStream_t stream) {
  const float* hs  = (const float*)d_in[0];
  const int*   seq = (const int*)d_in[1];
  const int*   ins = (const int*)d_in[2];
  const float* w_q = (const float*)d_in[3];
  const float* w_k = (const float*)d_in[4];
  const float* w_v = (const float*)d_in[5];
  const float* w_o = (const float*)d_in[6];
  const float* ln1 = (const float*)d_in[7];
  const float* ln2 = (const float*)d_in[8];
  const float* w_g = (const float*)d_in[9];
  const float* w_u = (const float*)d_in[10];
  const float* w_d = (const float*)d_in[11];
  const int  B     = in_sizes[1];
  const long total = (long)in_sizes[0] / DMODEL;

  const size_t WQKV_E = (size_t)QKVDIM * DMODEL;
  const size_t WO_E   = (size_t)DMODEL * DMODEL;
  const size_t WG_E   = (size_t)DFF * DMODEL;

  struct WS {
    int* dN; int* idx;
    bf16_t *Wqkv, *Wo, *Wg, *Wu, *Wd;
    bf16_t* kc; bf16_t* vc; float* hattn; bf16_t* gate;
    bf16_t* part;          // overlay region R: nm*16384 B (down partials)
    bf16_t* o;             // = R          (nm*4096 B; dead during down-GEMM)
    float*  h0;            // = R + nm*4096 (nm*8192 B; dead after p=0's Wo)
    bf16_t* x;             // after R, never aliased
    size_t bytes;
  };
  char* base = (char*)d_ws;
  auto mk = [&](long nm) {
    WS w; size_t o = 0;
    auto alloc = [&](size_t b) { char* p = base + o; o = (o + b + 255) & ~(size_t)255; return p; };
    w.dN    = (int*)alloc(4);
    w.idx   = (int*)alloc((size_t)nm * 4);
    w.Wqkv  = (bf16_t*)alloc(WQKV_E * 2);
    w.Wo    = (bf16_t*)alloc(WO_E * 2);
    w.Wg    = (bf16_t*)alloc(WG_E * 2);
    w.Wu    = (bf16_t*)alloc(WG_E * 2);
    w.Wd    = (bf16_t*)alloc(WG_E * 2);
    w.kc    = (bf16_t*)alloc((size_t)nm * NSTEPS * KVDIM * 2);
    w.vc    = (bf16_t*)alloc((size_t)nm * NSTEPS * KVDIM * 2);
    w.hattn = (float*)alloc((size_t)nm * DMODEL * 4);
    w.gate  = (bf16_t*)alloc((size_t)nm * DFF * 2);
    // overlay region R = down split-K partials (4 * nm * DMODEL bf16).
    // o and h0 live inside R; both are dead when the down-GEMM runs.
    char* R = alloc((size_t)nm * DMODEL * 2 * 4);   // nm*16384 B
    w.part  = (bf16_t*)R;
    w.o     = (bf16_t*)R;                            // nm*4096 B
    w.h0    = (float*)(R + (size_t)nm * DMODEL * 2); // nm*8192 B
    w.x     = (bf16_t*)alloc((size_t)nm * DMODEL * 2);
    w.bytes = o;
    return w;
  };
  long nm = ((total + 255) / 256) * 256;
  WS w = mk(nm);
  while (w.bytes > ws_size && nm > 256) { nm -= 256; w = mk(nm); }

  build_idx_kernel<<<1, 512, 0, stream>>>(seq, ins, B, w.idx, w.dN, (int)nm);
  gather_kernel<<<(uint32_t)nm, 256, 0, stream>>>(hs, w.idx, w.h0, w.dN);

  dim3 tb(256);
  wtrans_kernel<<<dim3(DMODEL/32, DMODEL/32), tb, 0, stream>>>(w_q, w.Wqkv, DMODEL, DMODEL);
  wtrans_kernel<<<dim3(KVDIM/32,  DMODEL/32), tb, 0, stream>>>(w_k, w.Wqkv + (size_t)QDIM * DMODEL, DMODEL, KVDIM);
  wtrans_kernel<<<dim3(KVDIM/32,  DMODEL/32), tb, 0, stream>>>(w_v, w.Wqkv + (size_t)(QDIM + KVDIM) * DMODEL, DMODEL, KVDIM);
  wtrans_kernel<<<dim3(DMODEL/32, DMODEL/32), tb, 0, stream>>>(w_o, w.Wo, DMODEL, DMODEL);
  wtrans_kernel<<<dim3(DFF/32,    DMODEL/32), tb, 0, stream>>>(w_g, w.Wg, DMODEL, DFF);
  wtrans_kernel<<<dim3(DFF/32,    DMODEL/32), tb, 0, stream>>>(w_u, w.Wu, DMODEL, DFF);
  wtrans_kernel<<<dim3(DMODEL/32, DFF/32),    tb, 0, stream>>>(w_d, w.Wd, DFF, DMODEL);

  const int gy2 = (int)(nm / 256);
  const uint32_t LDSB = 131072;        // 128 KiB dynamic LDS
  float* outF = (float*)d_out;
  const long zsD = (long)nm * DMODEL;   // partial z-stride, DMODEL cols
  const long zsQ = (long)nm * QKVDIM;   // partial z-stride, QKVDIM cols

  for (int p = 0; p < NSTEPS; ++p) {
    const float* hprev = (p == 0) ? w.h0 : outF + (size_t)(p - 1) * DMODEL;
    const long   hstr  = (p == 0) ? DMODEL : (long)NSTEPS * DMODEL;

    // ln1 for p>0 is fused into the previous step's reduce_norm (down).
    if (p == 0)
      rmsnorm_kernel<<<(uint32_t)nm, 256, 0, stream>>>(hprev, hstr, ln1, w.x, w.dN);

    // QKV: split-K=2 (192 blocks, nt=16); bf16 partials in w.gate (dead
    // between down-reduce and gate/up-GEMM). attn consumes directly.
    gemm256d_kernel<3><<<dim3(QKVDIM/256, gy2, 2), 512, LDSB, stream>>>(
        w.x, w.Wqkv, w.Wqkv, DMODEL, DMODEL/2, w.dN, zsQ, w.gate, QKVDIM);

    // fused reduce + RoPE + cache-append + attention
    attn_fused_kernel<<<dim3((uint32_t)nm, 8), 256, 0, stream>>>(
        w.gate, zsQ, w.kc, w.vc, w.o, p, w.dN);

    // Wo: split-K=4 (256 blocks, nt=8); partials in w.gate; fused reduce
    // adds residual hprev AND applies ln2 -> x.
    gemm256d_kernel<3><<<dim3(DMODEL/256, gy2, 4), 512, LDSB, stream>>>(
        w.o, w.Wo, w.Wo, DMODEL, DMODEL/4, w.dN, zsD, w.gate, DMODEL);
    reduce_norm_kernel<4><<<(uint32_t)nm, 256, 0, stream>>>(
        w.gate, zsD, hprev, hstr, w.hattn, DMODEL, w.x, ln2, w.dN);

    // fused gate+up: out = silu(x@Wg) * (x@Wu), no intermediate round-trip
    gemm256d_kernel<2><<<dim3(DFF/128, gy2, 1), 512, LDSB, stream>>>(
        w.x, w.Wg, w.Wu, DMODEL, DMODEL, w.dN, 0, w.gate, DFF);

    // down: split-K=4 -> partials overlay {o, h0} (dead here); fused
    // reduce adds hattn residual, writes outF[p], and (p<last) ln1->x.
    gemm256d_kernel<3><<<dim3(DMODEL/256, gy2, 4), 512, LDSB, stream>>>(
        w.gate, w.Wd, w.Wd, DFF, DFF/4, w.dN, zsD, w.part, DMODEL);
    reduce_norm_kernel<4><<<(uint32_t)nm, 256, 0, stream>>>(
        w.part, zsD, w.hattn, DMODEL, outF + (size_t)p * DMODEL, (long)NSTEPS * DMODEL,
        (p + 1 < NSTEPS) ? w.x : nullptr, ln1, w.dN);
  }
}